// Round 6
// baseline (203.689 us; speedup 1.0000x reference)
//
#include <hip/hip_runtime.h>
#include <hip/hip_fp16.h>

#define N_NODES 50000
#define N_EDGES 600000
#define D 128
#define N_RELS 460

typedef unsigned short u16;
typedef __attribute__((ext_vector_type(8))) short bf16x8;   // 8 bf16 (4 VGPRs)
typedef __attribute__((ext_vector_type(4))) float f32x4;

// workspace layout (element offsets, 4-byte elements)
enum : int {
    OFF_W       = 0,         //   384 floats  (w = fc1^T @ fc2^T, split w1|w2|w3)
    OFF_S1      = 384,       // 50000 floats
    OFF_S2      = 50384,     // 50000 floats
    OFF_S3      = 100384,    //   460 floats + pad
    OFF_COUNTS  = 100864,    // 50000 ints
    OFF_OFFSETS = 150864,    // 50001 ints + pad (block-local inclusive scans)
    OFF_BSUMS   = 200880,    //   256 ints (scanned block sums)
    OFF_RANK    = 201136,    // 600000 ints  (edge -> rank within its dst)
    OFF_PAIRS   = 801136,    // 600000 uints (CSR slot -> src(16b) | half(exp)(16b))
    OFF_HB      = 1401136,   // 6400000 bf16 = 3200000 float slots (h in bf16)
    OFF_WT      = 4601136,   // 16384 bf16 = 8192 float slots (loop_weight^T bf16)
};                           // total ~17.6 MiB

#define NODE_WAVES   25000   // 2 rows per wave
#define REL_WAVES    230     // 460 rels, 2 per wave
#define SCORE_BLOCKS 6308    // ceil((NODE_WAVES+REL_WAVES)/4)
#define CNT_BLOCKS   293     // ceil(75000/256): 8 edges per thread
#define ZERO_BLOCKS  196     // ceil(50000/256)
#define EDGE_BLOCKS  2344    // ceil(600000/256)
#define GEMM_BLOCKS  782     // ceil(50000/64)

__device__ __forceinline__ u16 f2bf(float f) {
    unsigned u = __float_as_uint(f);
    unsigned r = u + 0x7FFFu + ((u >> 16) & 1u);   // RNE
    return (u16)(r >> 16);
}
__device__ __forceinline__ float unp_ex(unsigned p) {
    return __half2float(__ushort_as_half((u16)(p >> 16)));
}

// ---------- K0: fused prep — w vector, Wt bf16 transpose, zero counts ----------
__global__ void k_prep(const float* __restrict__ fc1, const float* __restrict__ fc2,
                       const float* __restrict__ W,
                       float* __restrict__ w, u16* __restrict__ wt,
                       int* __restrict__ counts) {
    int b = blockIdx.x, t = threadIdx.x;
    if (b == 0) {
        for (int j = t; j < 3 * D; j += 256) {
            float acc = 0.f;
            for (int k = 0; k < D; ++k) acc += fc2[k] * fc1[k * 3 * D + j];
            w[j] = acc;
        }
    } else if (b <= 64) {
        int i = (b - 1) * 256 + t;                 // 16384 elems
        int k = i >> 7, n = i & 127;
        wt[n * D + k] = f2bf(W[k * D + n]);
    } else {
        int i = (b - 65) * 256 + t;                // zero 50000 ints
        if (i < N_NODES) counts[i] = 0;
    }
}

// ---------- K1: node scores (2 rows/wave) + bf16 cast; rel s3; histogram + RANK ----------
__global__ void k_scores_cast_count(const float* __restrict__ h,
                                    const float* __restrict__ emb_rel,
                                    const float* __restrict__ w,
                                    float* __restrict__ s1, float* __restrict__ s2,
                                    float* __restrict__ s3, u16* __restrict__ hb,
                                    const int* __restrict__ dst,
                                    int* __restrict__ counts,
                                    int* __restrict__ rank) {
    if (blockIdx.x < SCORE_BLOCKS) {
        int wv   = (blockIdx.x * blockDim.x + threadIdx.x) >> 6;
        int l    = threadIdx.x & 63;
        int half = l >> 5;                    // which of the wave's 2 rows
        int q    = l & 31;                    // 32 lanes x float4 = 128 floats/row
        if (wv < NODE_WAVES) {
            int r = wv * 2 + half;
            float4 hv = ((const float4*)(h + (size_t)r * D))[q];
            uint2 pk;
            pk.x = (unsigned)f2bf(hv.x) | ((unsigned)f2bf(hv.y) << 16);
            pk.y = (unsigned)f2bf(hv.z) | ((unsigned)f2bf(hv.w) << 16);
            ((uint2*)hb)[(size_t)r * 32 + q] = pk;            // 8B/lane coalesced
            float4 w1 = ((const float4*)w)[q];
            float4 w2 = ((const float4*)(w + D))[q];
            float a1 = hv.x * w1.x + hv.y * w1.y + hv.z * w1.z + hv.w * w1.w;
            float a2 = hv.x * w2.x + hv.y * w2.y + hv.z * w2.z + hv.w * w2.w;
            #pragma unroll
            for (int o = 16; o; o >>= 1) { a1 += __shfl_xor(a1, o); a2 += __shfl_xor(a2, o); }
            if (q == 0) { s1[r] = a1; s2[r] = a2; }           // lanes 0 and 32
        } else if (wv < NODE_WAVES + REL_WAVES) {
            int r = (wv - NODE_WAVES) * 2 + half;             // 460 = 230*2 exact
            float4 rv = ((const float4*)(emb_rel + (size_t)r * D))[q];
            float4 w3 = ((const float4*)(w + 2 * D))[q];
            float a3 = rv.x * w3.x + rv.y * w3.y + rv.z * w3.z + rv.w * w3.w;
            #pragma unroll
            for (int o = 16; o; o >>= 1) a3 += __shfl_xor(a3, o);
            if (q == 0) s3[r] = a3;
        }
    } else {
        int i = (blockIdx.x - SCORE_BLOCKS) * 256 + threadIdx.x;   // 8 edges/thread
        if (i < N_EDGES / 8) {
            int4 da = ((const int4*)dst)[2 * i];
            int4 db = ((const int4*)dst)[2 * i + 1];
            int4 ra, rb;
            ra.x = atomicAdd(&counts[da.x], 1);
            ra.y = atomicAdd(&counts[da.y], 1);
            ra.z = atomicAdd(&counts[da.z], 1);
            ra.w = atomicAdd(&counts[da.w], 1);
            rb.x = atomicAdd(&counts[db.x], 1);
            rb.y = atomicAdd(&counts[db.y], 1);
            rb.z = atomicAdd(&counts[db.z], 1);
            rb.w = atomicAdd(&counts[db.w], 1);
            ((int4*)rank)[2 * i]     = ra;                    // coalesced
            ((int4*)rank)[2 * i + 1] = rb;
        }
    }
}

// ---------- scan1: per-block inclusive scan; offsets[i+1]=incl(i), bsums[b]=sum ----------
__global__ void k_scan1(const int* __restrict__ counts, int* __restrict__ offsets,
                        int* __restrict__ bsums) {
    __shared__ int s[256];
    int i = blockIdx.x * 256 + threadIdx.x;
    int v = (i < N_NODES) ? counts[i] : 0;
    s[threadIdx.x] = v;
    __syncthreads();
    for (int off = 1; off < 256; off <<= 1) {
        int t = (threadIdx.x >= off) ? s[threadIdx.x - off] : 0;
        __syncthreads();
        s[threadIdx.x] += t;
        __syncthreads();
    }
    if (i < N_NODES) offsets[i + 1] = s[threadIdx.x];
    if (blockIdx.x == 0 && threadIdx.x == 0) offsets[0] = 0;
    if (threadIdx.x == 255) bsums[blockIdx.x] = s[255];
}

// ---------- scan2: inclusive scan of block sums (196 <= 256) ----------
__global__ void k_scan2(int* __restrict__ bsums, int nb) {
    __shared__ int s[256];
    int t = threadIdx.x;
    s[t] = (t < nb) ? bsums[t] : 0;
    __syncthreads();
    for (int off = 1; off < 256; off <<= 1) {
        int v = (t >= off) ? s[t - off] : 0;
        __syncthreads();
        s[t] += v;
        __syncthreads();
    }
    if (t < nb) bsums[t] = s[t];
}

// global exclusive offset of node d
__device__ __forceinline__ int g_off(const int* offsets, const int* bsums, int d) {
    int blk = d >> 8;
    int base = blk ? bsums[blk - 1] : 0;
    return ((d & 255) ? offsets[d] : 0) + base;
}

// ---------- K3: fused {atomic-free CSR fill} + {LDS-free MFMA self-loop GEMM} ----------
// A-frag: A[m=lane&15][k=quad*8+j]; B-frag: B[k=quad*8+j][n=lane&15];
// C/D: D[m=quad*4+reg][n=lane&15]. Wt[n][k] row-major -> B loads contiguous 16B.
__global__ __launch_bounds__(256) void k_scatter_gemm(
        const int* __restrict__ src, const int* __restrict__ dst,
        const int* __restrict__ typ, const int* __restrict__ rank,
        const float* __restrict__ s1, const float* __restrict__ s2,
        const float* __restrict__ s3,
        const int* __restrict__ offsets, const int* __restrict__ bsums,
        unsigned* __restrict__ pairs,
        const u16* __restrict__ hb, const u16* __restrict__ wt,
        float* __restrict__ out) {
    if (blockIdx.x < EDGE_BLOCKS) {
        int e = blockIdx.x * blockDim.x + threadIdx.x;
        if (e >= N_EDGES) return;
        int d = dst[e];
        int sidx = src[e];
        float x = s1[sidx] + s2[d] + s3[typ[e]];
        float lv = (x > 0.f) ? x : 0.01f * x;
        float ex = __expf(lv);             // |x| <~ 3; shift-invariant, no max-sub
        int slot = g_off(offsets, bsums, d) + rank[e];   // NO atomic
        pairs[slot] = (unsigned)sidx
                    | ((unsigned)__half_as_ushort(__float2half(ex)) << 16);
    } else {
        int b = blockIdx.x - EDGE_BLOCKS;
        int t = threadIdx.x;
        int wave = t >> 6, lane = t & 63;
        int quad = lane >> 4, m16 = lane & 15;
        int nbase = b * 64 + wave * 16;

        f32x4 acc[8];
        #pragma unroll
        for (int cg = 0; cg < 8; ++cg) acc[cg] = (f32x4){0.f, 0.f, 0.f, 0.f};

        int arow = nbase + m16;
        if (arow >= N_NODES) arow = N_NODES - 1;         // clamp; stores guarded
        const u16* aptr = hb + (size_t)arow * D + quad * 8;

        #pragma unroll
        for (int k0 = 0; k0 < D; k0 += 32) {
            bf16x8 a = *(const bf16x8*)(aptr + k0);
            #pragma unroll
            for (int cg = 0; cg < 8; ++cg) {
                bf16x8 bb = *(const bf16x8*)(&wt[(size_t)(cg * 16 + m16) * D + k0 + quad * 8]);
                acc[cg] = __builtin_amdgcn_mfma_f32_16x16x32_bf16(a, bb, acc[cg], 0, 0, 0);
            }
        }
        #pragma unroll
        for (int reg = 0; reg < 4; ++reg) {
            int row = nbase + quad * 4 + reg;
            if (row < N_NODES) {
                #pragma unroll
                for (int cg = 0; cg < 8; ++cg)
                    out[(size_t)row * D + cg * 16 + m16] = acc[cg][reg];
            }
        }
    }
}

// ---------- K4: gather — 4 nodes/wave, 16-lane groups, 16B row loads ----------
__global__ void k_gather(const u16* __restrict__ hb, const int* __restrict__ offsets,
                         const int* __restrict__ bsums,
                         const unsigned* __restrict__ pairs, float* __restrict__ out) {
    int n  = (blockIdx.x * blockDim.x + threadIdx.x) >> 4;   // one 16-lane group per node
    int gl = threadIdx.x & 15;
    if (n >= N_NODES) return;
    int blk = n >> 8;
    int base = blk ? bsums[blk - 1] : 0;
    int beg = ((n & 255) ? offsets[n] : 0) + base;
    int end = offsets[n + 1] + base;
    if (beg == end) return;                              // deg 0: out = h@W only

    float den = 0.f;
    for (int i = beg + gl; i < end; i += 16) den += unp_ex(pairs[i]);
    #pragma unroll
    for (int o = 8; o; o >>= 1) den += __shfl_xor(den, o, 16);
    float inv = 1.f / den;

    // lane gl covers columns [8*gl, 8*gl+8)
    f32x4 accA = {0.f, 0.f, 0.f, 0.f}, accB = {0.f, 0.f, 0.f, 0.f};
    for (int cb = beg; cb < end; cb += 16) {
        int i = cb + gl;
        unsigned p = (i < end) ? pairs[i] : 0u;
        int   msrc = (int)(p & 0xFFFFu);
        float mco  = (i < end) ? unp_ex(p) * inv : 0.f;
        int cnt = min(16, end - cb);
        int j = 0;
        for (; j + 1 < cnt; j += 2) {
            int   a0 = __shfl(msrc, j, 16), a1 = __shfl(msrc, j + 1, 16);
            float c0 = __shfl(mco,  j, 16), c1 = __shfl(mco,  j + 1, 16);
            uint4 u0 = ((const uint4*)(hb + (size_t)a0 * D))[gl];
            uint4 u1 = ((const uint4*)(hb + (size_t)a1 * D))[gl];
            accA.x += c0 * __uint_as_float(u0.x << 16) + c1 * __uint_as_float(u1.x << 16);
            accA.y += c0 * __uint_as_float(u0.x & 0xFFFF0000u) + c1 * __uint_as_float(u1.x & 0xFFFF0000u);
            accA.z += c0 * __uint_as_float(u0.y << 16) + c1 * __uint_as_float(u1.y << 16);
            accA.w += c0 * __uint_as_float(u0.y & 0xFFFF0000u) + c1 * __uint_as_float(u1.y & 0xFFFF0000u);
            accB.x += c0 * __uint_as_float(u0.z << 16) + c1 * __uint_as_float(u1.z << 16);
            accB.y += c0 * __uint_as_float(u0.z & 0xFFFF0000u) + c1 * __uint_as_float(u1.z & 0xFFFF0000u);
            accB.z += c0 * __uint_as_float(u0.w << 16) + c1 * __uint_as_float(u1.w << 16);
            accB.w += c0 * __uint_as_float(u0.w & 0xFFFF0000u) + c1 * __uint_as_float(u1.w & 0xFFFF0000u);
        }
        if (j < cnt) {
            int   a0 = __shfl(msrc, j, 16);
            float c0 = __shfl(mco,  j, 16);
            uint4 u0 = ((const uint4*)(hb + (size_t)a0 * D))[gl];
            accA.x += c0 * __uint_as_float(u0.x << 16);
            accA.y += c0 * __uint_as_float(u0.x & 0xFFFF0000u);
            accA.z += c0 * __uint_as_float(u0.y << 16);
            accA.w += c0 * __uint_as_float(u0.y & 0xFFFF0000u);
            accB.x += c0 * __uint_as_float(u0.z << 16);
            accB.y += c0 * __uint_as_float(u0.z & 0xFFFF0000u);
            accB.z += c0 * __uint_as_float(u0.w << 16);
            accB.w += c0 * __uint_as_float(u0.w & 0xFFFF0000u);
        }
    }
    float* op = out + (size_t)n * D + gl * 8;
    float4 o0 = *(float4*)op, o1 = *(float4*)(op + 4);
    o0.x += accA.x; o0.y += accA.y; o0.z += accA.z; o0.w += accA.w;
    o1.x += accB.x; o1.y += accB.y; o1.z += accB.z; o1.w += accB.w;
    *(float4*)op = o0; *(float4*)(op + 4) = o1;
}

extern "C" void kernel_launch(void* const* d_in, const int* in_sizes, int n_in,
                              void* d_out, int out_size, void* d_ws, size_t ws_size,
                              hipStream_t stream) {
    const float* h       = (const float*)d_in[0];
    const float* emb_rel = (const float*)d_in[1];
    const float* fc1     = (const float*)d_in[2];   // [D, 3D]
    const float* fc2     = (const float*)d_in[3];   // [1, D]
    const float* loopw   = (const float*)d_in[4];   // [D, D]
    const int*   esrc    = (const int*)d_in[5];
    const int*   edst    = (const int*)d_in[6];
    const int*   etyp    = (const int*)d_in[7];
    float* out = (float*)d_out;
    float* ws  = (float*)d_ws;

    float*    w       = ws + OFF_W;
    float*    s1      = ws + OFF_S1;
    float*    s2      = ws + OFF_S2;
    float*    s3      = ws + OFF_S3;
    int*      counts  = (int*)(ws + OFF_COUNTS);
    int*      offsets = (int*)(ws + OFF_OFFSETS);
    int*      bsums   = (int*)(ws + OFF_BSUMS);
    int*      rank    = (int*)(ws + OFF_RANK);
    unsigned* pairs   = (unsigned*)(ws + OFF_PAIRS);
    u16*      hb      = (u16*)(ws + OFF_HB);
    u16*      wt      = (u16*)(ws + OFF_WT);

    // 1: w + Wt^T bf16 + zero counts
    k_prep<<<1 + 64 + ZERO_BLOCKS, 256, 0, stream>>>(fc1, fc2, loopw, w, wt, counts);

    // 2: node scores + bf16 cast + edge histogram (saving per-edge rank)
    k_scores_cast_count<<<SCORE_BLOCKS + CNT_BLOCKS, 256, 0, stream>>>(
        h, emb_rel, w, s1, s2, s3, hb, edst, counts, rank);

    // 3,4: two-level scan (base-add folded into consumers)
    k_scan1<<<ZERO_BLOCKS, 256, 0, stream>>>(counts, offsets, bsums);
    k_scan2<<<1, 256, 0, stream>>>(bsums, ZERO_BLOCKS);

    // 5: atomic-free CSR fill overlapped with MFMA self-loop GEMM
    k_scatter_gemm<<<EDGE_BLOCKS + GEMM_BLOCKS, 256, 0, stream>>>(
        esrc, edst, etyp, rank, s1, s2, s3, offsets, bsums, pairs, hb, wt, out);

    // 6: softmax-normalized weighted gather (RMW out)
    k_gather<<<(N_NODES * 16 + 255) / 256, 256, 0, stream>>>(hb, offsets, bsums, pairs, out);
}

// Round 7
// 201.595 us; speedup vs baseline: 1.0104x; 1.0104x over previous
//
#include <hip/hip_runtime.h>
#include <hip/hip_fp16.h>

#define N_NODES 50000
#define N_EDGES 600000
#define D 128
#define N_RELS 460

typedef unsigned short u16;
typedef __attribute__((ext_vector_type(8))) short bf16x8;   // 8 bf16 (4 VGPRs)
typedef __attribute__((ext_vector_type(4))) float f32x4;

// workspace layout (element offsets, 4-byte elements)
enum : int {
    OFF_W       = 0,         //   384 floats  (w = fc1^T @ fc2^T, split w1|w2|w3)
    OFF_S1      = 384,       // 50000 floats
    OFF_S2      = 50384,     // 50000 floats
    OFF_S3      = 100384,    //   460 floats + pad
    OFF_COUNTS  = 100864,    // 50000 ints
    OFF_OFFSETS = 150864,    // 50001 ints + pad (block-local inclusive scans)
    OFF_BSUMS   = 200880,    //   256 ints (scanned block sums)
    OFF_RANK    = 201136,    // 600000 ints  (edge -> rank within its dst)
    OFF_PAIRS   = 801136,    // 600000 uints (CSR slot -> src(16b) | half(exp)(16b))
    OFF_HB      = 1401136,   // 6400000 bf16 = 3200000 float slots (h in bf16)
    OFF_WT      = 4601136,   // 16384 bf16 = 8192 float slots (loop_weight^T bf16)
};                           // total ~17.6 MiB

#define NODE_WAVES   25000   // 2 rows per wave
#define REL_WAVES    230     // 460 rels, 2 per wave
#define SCORE_BLOCKS 6308    // ceil((NODE_WAVES+REL_WAVES)/4)
#define CNT_BLOCKS   586     // ceil(150000/256): 4 edges per thread
#define ZERO_BLOCKS  196     // ceil(50000/256)
#define EDGE_BLOCKS  2344    // ceil(600000/256)
#define GEMM_BLOCKS  782     // ceil(50000/64)

__device__ __forceinline__ u16 f2bf(float f) {
    unsigned u = __float_as_uint(f);
    unsigned r = u + 0x7FFFu + ((u >> 16) & 1u);   // RNE
    return (u16)(r >> 16);
}
__device__ __forceinline__ float unp_ex(unsigned p) {
    return __half2float(__ushort_as_half((u16)(p >> 16)));
}

// ---------- K0: fused prep — w vector, Wt bf16 transpose, zero counts ----------
__global__ void k_prep(const float* __restrict__ fc1, const float* __restrict__ fc2,
                       const float* __restrict__ W,
                       float* __restrict__ w, u16* __restrict__ wt,
                       int* __restrict__ counts) {
    int b = blockIdx.x, t = threadIdx.x;
    if (b == 0) {
        for (int j = t; j < 3 * D; j += 256) {
            float acc = 0.f;
            for (int k = 0; k < D; ++k) acc += fc2[k] * fc1[k * 3 * D + j];
            w[j] = acc;
        }
    } else if (b <= 64) {
        int i = (b - 1) * 256 + t;                 // 16384 elems
        int k = i >> 7, n = i & 127;
        wt[n * D + k] = f2bf(W[k * D + n]);
    } else {
        int i = (b - 65) * 256 + t;                // zero 50000 ints
        if (i < N_NODES) counts[i] = 0;
    }
}

// ---------- K1a: standalone edge histogram + rank (counts stays L2-hot) ----------
__global__ void k_count(const int* __restrict__ dst, int* __restrict__ counts,
                        int* __restrict__ rank) {
    int i = blockIdx.x * blockDim.x + threadIdx.x;     // 4 edges/thread, int4
    if (i < N_EDGES / 4) {
        int4 d4 = ((const int4*)dst)[i];
        int4 r4;
        r4.x = atomicAdd(&counts[d4.x], 1);
        r4.y = atomicAdd(&counts[d4.y], 1);
        r4.z = atomicAdd(&counts[d4.z], 1);
        r4.w = atomicAdd(&counts[d4.w], 1);
        ((int4*)rank)[i] = r4;                         // coalesced
    }
}

// ---------- K1b: node scores (2 rows/wave) + bf16 cast; rel s3 (pure streaming) ----------
__global__ void k_scores_cast(const float* __restrict__ h,
                              const float* __restrict__ emb_rel,
                              const float* __restrict__ w,
                              float* __restrict__ s1, float* __restrict__ s2,
                              float* __restrict__ s3, u16* __restrict__ hb) {
    int wv   = (blockIdx.x * blockDim.x + threadIdx.x) >> 6;
    int l    = threadIdx.x & 63;
    int half = l >> 5;                    // which of the wave's 2 rows
    int q    = l & 31;                    // 32 lanes x float4 = 128 floats/row
    if (wv < NODE_WAVES) {
        int r = wv * 2 + half;
        float4 hv = ((const float4*)(h + (size_t)r * D))[q];
        uint2 pk;
        pk.x = (unsigned)f2bf(hv.x) | ((unsigned)f2bf(hv.y) << 16);
        pk.y = (unsigned)f2bf(hv.z) | ((unsigned)f2bf(hv.w) << 16);
        ((uint2*)hb)[(size_t)r * 32 + q] = pk;            // 8B/lane coalesced
        float4 w1 = ((const float4*)w)[q];
        float4 w2 = ((const float4*)(w + D))[q];
        float a1 = hv.x * w1.x + hv.y * w1.y + hv.z * w1.z + hv.w * w1.w;
        float a2 = hv.x * w2.x + hv.y * w2.y + hv.z * w2.z + hv.w * w2.w;
        #pragma unroll
        for (int o = 16; o; o >>= 1) { a1 += __shfl_xor(a1, o); a2 += __shfl_xor(a2, o); }
        if (q == 0) { s1[r] = a1; s2[r] = a2; }           // lanes 0 and 32
    } else if (wv < NODE_WAVES + REL_WAVES) {
        int r = (wv - NODE_WAVES) * 2 + half;             // 460 = 230*2 exact
        float4 rv = ((const float4*)(emb_rel + (size_t)r * D))[q];
        float4 w3 = ((const float4*)(w + 2 * D))[q];
        float a3 = rv.x * w3.x + rv.y * w3.y + rv.z * w3.z + rv.w * w3.w;
        #pragma unroll
        for (int o = 16; o; o >>= 1) a3 += __shfl_xor(a3, o);
        if (q == 0) s3[r] = a3;
    }
}

// ---------- scan1: per-block inclusive scan; offsets[i+1]=incl(i), bsums[b]=sum ----------
__global__ void k_scan1(const int* __restrict__ counts, int* __restrict__ offsets,
                        int* __restrict__ bsums) {
    __shared__ int s[256];
    int i = blockIdx.x * 256 + threadIdx.x;
    int v = (i < N_NODES) ? counts[i] : 0;
    s[threadIdx.x] = v;
    __syncthreads();
    for (int off = 1; off < 256; off <<= 1) {
        int t = (threadIdx.x >= off) ? s[threadIdx.x - off] : 0;
        __syncthreads();
        s[threadIdx.x] += t;
        __syncthreads();
    }
    if (i < N_NODES) offsets[i + 1] = s[threadIdx.x];
    if (blockIdx.x == 0 && threadIdx.x == 0) offsets[0] = 0;
    if (threadIdx.x == 255) bsums[blockIdx.x] = s[255];
}

// ---------- scan2: inclusive scan of block sums (196 <= 256) ----------
__global__ void k_scan2(int* __restrict__ bsums, int nb) {
    __shared__ int s[256];
    int t = threadIdx.x;
    s[t] = (t < nb) ? bsums[t] : 0;
    __syncthreads();
    for (int off = 1; off < 256; off <<= 1) {
        int v = (t >= off) ? s[t - off] : 0;
        __syncthreads();
        s[t] += v;
        __syncthreads();
    }
    if (t < nb) bsums[t] = s[t];
}

// global exclusive offset of node d
__device__ __forceinline__ int g_off(const int* offsets, const int* bsums, int d) {
    int blk = d >> 8;
    int base = blk ? bsums[blk - 1] : 0;
    return ((d & 255) ? offsets[d] : 0) + base;
}

// ---------- K3: fused {atomic-free CSR fill} + {LDS-free MFMA self-loop GEMM} ----------
// A-frag: A[m=lane&15][k=quad*8+j]; B-frag: B[k=quad*8+j][n=lane&15];
// C/D: D[m=quad*4+reg][n=lane&15]. Wt[n][k] row-major -> B loads contiguous 16B.
__global__ __launch_bounds__(256) void k_scatter_gemm(
        const int* __restrict__ src, const int* __restrict__ dst,
        const int* __restrict__ typ, const int* __restrict__ rank,
        const float* __restrict__ s1, const float* __restrict__ s2,
        const float* __restrict__ s3,
        const int* __restrict__ offsets, const int* __restrict__ bsums,
        unsigned* __restrict__ pairs,
        const u16* __restrict__ hb, const u16* __restrict__ wt,
        float* __restrict__ out) {
    if (blockIdx.x < EDGE_BLOCKS) {
        int e = blockIdx.x * blockDim.x + threadIdx.x;
        if (e >= N_EDGES) return;
        int d = dst[e];
        int sidx = src[e];
        float x = s1[sidx] + s2[d] + s3[typ[e]];
        float lv = (x > 0.f) ? x : 0.01f * x;
        float ex = __expf(lv);             // |x| <~ 3; shift-invariant, no max-sub
        int slot = g_off(offsets, bsums, d) + rank[e];   // NO atomic
        pairs[slot] = (unsigned)sidx
                    | ((unsigned)__half_as_ushort(__float2half(ex)) << 16);
    } else {
        int b = blockIdx.x - EDGE_BLOCKS;
        int t = threadIdx.x;
        int wave = t >> 6, lane = t & 63;
        int quad = lane >> 4, m16 = lane & 15;
        int nbase = b * 64 + wave * 16;

        f32x4 acc[8];
        #pragma unroll
        for (int cg = 0; cg < 8; ++cg) acc[cg] = (f32x4){0.f, 0.f, 0.f, 0.f};

        int arow = nbase + m16;
        if (arow >= N_NODES) arow = N_NODES - 1;         // clamp; stores guarded
        const u16* aptr = hb + (size_t)arow * D + quad * 8;

        #pragma unroll
        for (int k0 = 0; k0 < D; k0 += 32) {
            bf16x8 a = *(const bf16x8*)(aptr + k0);
            #pragma unroll
            for (int cg = 0; cg < 8; ++cg) {
                bf16x8 bb = *(const bf16x8*)(&wt[(size_t)(cg * 16 + m16) * D + k0 + quad * 8]);
                acc[cg] = __builtin_amdgcn_mfma_f32_16x16x32_bf16(a, bb, acc[cg], 0, 0, 0);
            }
        }
        #pragma unroll
        for (int reg = 0; reg < 4; ++reg) {
            int row = nbase + quad * 4 + reg;
            if (row < N_NODES) {
                #pragma unroll
                for (int cg = 0; cg < 8; ++cg)
                    out[(size_t)row * D + cg * 16 + m16] = acc[cg][reg];
            }
        }
    }
}

// ---------- K4: gather — 4 nodes/wave, 16-lane groups, 16B row loads ----------
__global__ void k_gather(const u16* __restrict__ hb, const int* __restrict__ offsets,
                         const int* __restrict__ bsums,
                         const unsigned* __restrict__ pairs, float* __restrict__ out) {
    int n  = (blockIdx.x * blockDim.x + threadIdx.x) >> 4;   // one 16-lane group per node
    int gl = threadIdx.x & 15;
    if (n >= N_NODES) return;
    int blk = n >> 8;
    int base = blk ? bsums[blk - 1] : 0;
    int beg = ((n & 255) ? offsets[n] : 0) + base;
    int end = offsets[n + 1] + base;
    if (beg == end) return;                              // deg 0: out = h@W only

    float den = 0.f;
    for (int i = beg + gl; i < end; i += 16) den += unp_ex(pairs[i]);
    #pragma unroll
    for (int o = 8; o; o >>= 1) den += __shfl_xor(den, o, 16);
    float inv = 1.f / den;

    // lane gl covers columns [8*gl, 8*gl+8)
    f32x4 accA = {0.f, 0.f, 0.f, 0.f}, accB = {0.f, 0.f, 0.f, 0.f};
    for (int cb = beg; cb < end; cb += 16) {
        int i = cb + gl;
        unsigned p = (i < end) ? pairs[i] : 0u;
        int   msrc = (int)(p & 0xFFFFu);
        float mco  = (i < end) ? unp_ex(p) * inv : 0.f;
        int cnt = min(16, end - cb);
        int j = 0;
        for (; j + 1 < cnt; j += 2) {
            int   a0 = __shfl(msrc, j, 16), a1 = __shfl(msrc, j + 1, 16);
            float c0 = __shfl(mco,  j, 16), c1 = __shfl(mco,  j + 1, 16);
            uint4 u0 = ((const uint4*)(hb + (size_t)a0 * D))[gl];
            uint4 u1 = ((const uint4*)(hb + (size_t)a1 * D))[gl];
            accA.x += c0 * __uint_as_float(u0.x << 16) + c1 * __uint_as_float(u1.x << 16);
            accA.y += c0 * __uint_as_float(u0.x & 0xFFFF0000u) + c1 * __uint_as_float(u1.x & 0xFFFF0000u);
            accA.z += c0 * __uint_as_float(u0.y << 16) + c1 * __uint_as_float(u1.y << 16);
            accA.w += c0 * __uint_as_float(u0.y & 0xFFFF0000u) + c1 * __uint_as_float(u1.y & 0xFFFF0000u);
            accB.x += c0 * __uint_as_float(u0.z << 16) + c1 * __uint_as_float(u1.z << 16);
            accB.y += c0 * __uint_as_float(u0.z & 0xFFFF0000u) + c1 * __uint_as_float(u1.z & 0xFFFF0000u);
            accB.z += c0 * __uint_as_float(u0.w << 16) + c1 * __uint_as_float(u1.w << 16);
            accB.w += c0 * __uint_as_float(u0.w & 0xFFFF0000u) + c1 * __uint_as_float(u1.w & 0xFFFF0000u);
        }
        if (j < cnt) {
            int   a0 = __shfl(msrc, j, 16);
            float c0 = __shfl(mco,  j, 16);
            uint4 u0 = ((const uint4*)(hb + (size_t)a0 * D))[gl];
            accA.x += c0 * __uint_as_float(u0.x << 16);
            accA.y += c0 * __uint_as_float(u0.x & 0xFFFF0000u);
            accA.z += c0 * __uint_as_float(u0.y << 16);
            accA.w += c0 * __uint_as_float(u0.y & 0xFFFF0000u);
            accB.x += c0 * __uint_as_float(u0.z << 16);
            accB.y += c0 * __uint_as_float(u0.z & 0xFFFF0000u);
            accB.z += c0 * __uint_as_float(u0.w << 16);
            accB.w += c0 * __uint_as_float(u0.w & 0xFFFF0000u);
        }
    }
    float* op = out + (size_t)n * D + gl * 8;
    float4 o0 = *(float4*)op, o1 = *(float4*)(op + 4);
    o0.x += accA.x; o0.y += accA.y; o0.z += accA.z; o0.w += accA.w;
    o1.x += accB.x; o1.y += accB.y; o1.z += accB.z; o1.w += accB.w;
    *(float4*)op = o0; *(float4*)(op + 4) = o1;
}

extern "C" void kernel_launch(void* const* d_in, const int* in_sizes, int n_in,
                              void* d_out, int out_size, void* d_ws, size_t ws_size,
                              hipStream_t stream) {
    const float* h       = (const float*)d_in[0];
    const float* emb_rel = (const float*)d_in[1];
    const float* fc1     = (const float*)d_in[2];   // [D, 3D]
    const float* fc2     = (const float*)d_in[3];   // [1, D]
    const float* loopw   = (const float*)d_in[4];   // [D, D]
    const int*   esrc    = (const int*)d_in[5];
    const int*   edst    = (const int*)d_in[6];
    const int*   etyp    = (const int*)d_in[7];
    float* out = (float*)d_out;
    float* ws  = (float*)d_ws;

    float*    w       = ws + OFF_W;
    float*    s1      = ws + OFF_S1;
    float*    s2      = ws + OFF_S2;
    float*    s3      = ws + OFF_S3;
    int*      counts  = (int*)(ws + OFF_COUNTS);
    int*      offsets = (int*)(ws + OFF_OFFSETS);
    int*      bsums   = (int*)(ws + OFF_BSUMS);
    int*      rank    = (int*)(ws + OFF_RANK);
    unsigned* pairs   = (unsigned*)(ws + OFF_PAIRS);
    u16*      hb      = (u16*)(ws + OFF_HB);
    u16*      wt      = (u16*)(ws + OFF_WT);

    // 1: w + Wt^T bf16 + zero counts
    k_prep<<<1 + 64 + ZERO_BLOCKS, 256, 0, stream>>>(fc1, fc2, loopw, w, wt, counts);

    // 2: standalone histogram + rank (counts L2-resident, no streaming interference)
    k_count<<<CNT_BLOCKS, 256, 0, stream>>>(edst, counts, rank);

    // 3: node scores + bf16 cast (pure streaming)
    k_scores_cast<<<SCORE_BLOCKS, 256, 0, stream>>>(h, emb_rel, w, s1, s2, s3, hb);

    // 4,5: two-level scan (base-add folded into consumers)
    k_scan1<<<ZERO_BLOCKS, 256, 0, stream>>>(counts, offsets, bsums);
    k_scan2<<<1, 256, 0, stream>>>(bsums, ZERO_BLOCKS);

    // 6: atomic-free CSR fill overlapped with MFMA self-loop GEMM
    k_scatter_gemm<<<EDGE_BLOCKS + GEMM_BLOCKS, 256, 0, stream>>>(
        esrc, edst, etyp, rank, s1, s2, s3, offsets, bsums, pairs, hb, wt, out);

    // 7: softmax-normalized weighted gather (RMW out)
    k_gather<<<(N_NODES * 16 + 255) / 256, 256, 0, stream>>>(hb, offsets, bsums, pairs, out);
}

// Round 8
// 196.370 us; speedup vs baseline: 1.0373x; 1.0266x over previous
//
#include <hip/hip_runtime.h>

#define N_NODES 50000
#define N_EDGES 600000
#define D 128
#define N_RELS 460

typedef unsigned short u16;
typedef __attribute__((ext_vector_type(8))) short bf16x8;   // 8 bf16 (4 VGPRs)
typedef __attribute__((ext_vector_type(4))) float f32x4;

// workspace layout (element offsets, 4-byte elements)
enum : int {
    OFF_W       = 0,         //   384 floats  (w = fc1^T @ fc2^T, split w1|w2|w3)
    OFF_S1      = 384,       // 50000 floats
    OFF_S2      = 50384,     // 50000 floats
    OFF_S3      = 100384,    //   460 floats + pad
    OFF_COUNTS  = 100864,    // 50000 ints
    OFF_OFFSETS = 150864,    // 50001 ints + pad (block-local inclusive scans)
    OFF_BSUMS   = 200880,    //   256 ints (scanned block sums)
    OFF_RANK    = 201136,    // 600000 ints  (edge -> rank within its dst)
    OFF_CSR     = 801136,    // 600000 uints (CSR slot -> src(16b) | typ(16b))
    OFF_HB      = 1401136,   // 6400000 bf16 = 3200000 float slots (h in bf16)
    OFF_WT      = 4601136,   // 16384 bf16 = 8192 float slots (loop_weight^T bf16)
};                           // total ~17.6 MiB

#define NODE_WAVES   12500   // 4 rows per wave
#define REL_WAVES    115     // 460 rels, 4 per wave
#define SCORE_BLOCKS 3154    // ceil((NODE_WAVES+REL_WAVES)/4)
#define CNT_BLOCKS   586     // ceil(150000/256): 4 edges per thread
#define ZERO_BLOCKS  196     // ceil(50000/256)
#define FILL_BLOCKS  1172    // ceil(300000/256): 2 edges per thread
#define GEMM_BLOCKS  782     // ceil(50000/64)

__device__ __forceinline__ u16 f2bf(float f) {
    unsigned u = __float_as_uint(f);
    unsigned r = u + 0x7FFFu + ((u >> 16) & 1u);   // RNE
    return (u16)(r >> 16);
}

// ---------- K0: fused prep — w vector, Wt bf16 transpose, zero counts ----------
__global__ void k_prep(const float* __restrict__ fc1, const float* __restrict__ fc2,
                       const float* __restrict__ W,
                       float* __restrict__ w, u16* __restrict__ wt,
                       int* __restrict__ counts) {
    int b = blockIdx.x, t = threadIdx.x;
    if (b == 0) {
        for (int j = t; j < 3 * D; j += 256) {
            float acc = 0.f;
            for (int k = 0; k < D; ++k) acc += fc2[k] * fc1[k * 3 * D + j];
            w[j] = acc;
        }
    } else if (b <= 64) {
        int i = (b - 1) * 256 + t;                 // 16384 elems
        int k = i >> 7, n = i & 127;
        wt[n * D + k] = f2bf(W[k * D + n]);
    } else {
        int i = (b - 65) * 256 + t;                // zero 50000 ints
        if (i < N_NODES) counts[i] = 0;
    }
}

// ---------- K1: edge histogram + rank (counts stays L2-hot) ----------
__global__ void k_count(const int* __restrict__ dst, int* __restrict__ counts,
                        int* __restrict__ rank) {
    int i = blockIdx.x * blockDim.x + threadIdx.x;     // 4 edges/thread, int4
    if (i < N_EDGES / 4) {
        int4 d4 = ((const int4*)dst)[i];
        int4 r4;
        r4.x = atomicAdd(&counts[d4.x], 1);
        r4.y = atomicAdd(&counts[d4.y], 1);
        r4.z = atomicAdd(&counts[d4.z], 1);
        r4.w = atomicAdd(&counts[d4.w], 1);
        ((int4*)rank)[i] = r4;                         // coalesced
    }
}

// ---------- K2: node scores (4 rows/wave) + bf16 cast; rel s3 ----------
__global__ void k_scores_cast(const float* __restrict__ h,
                              const float* __restrict__ emb_rel,
                              const float* __restrict__ w,
                              float* __restrict__ s1, float* __restrict__ s2,
                              float* __restrict__ s3, u16* __restrict__ hb) {
    int wv = (blockIdx.x * blockDim.x + threadIdx.x) >> 6;
    int l  = threadIdx.x & 63;
    int sub = l >> 4;                     // which of the wave's 4 rows
    int q   = l & 15;                     // 16 lanes x 8 floats = 128 floats/row
    if (wv < NODE_WAVES) {
        int r = wv * 4 + sub;
        const float* hp = h + (size_t)r * D + q * 8;
        float4 h0 = *(const float4*)hp;
        float4 h1 = *(const float4*)(hp + 4);
        uint4 pk;
        pk.x = (unsigned)f2bf(h0.x) | ((unsigned)f2bf(h0.y) << 16);
        pk.y = (unsigned)f2bf(h0.z) | ((unsigned)f2bf(h0.w) << 16);
        pk.z = (unsigned)f2bf(h1.x) | ((unsigned)f2bf(h1.y) << 16);
        pk.w = (unsigned)f2bf(h1.z) | ((unsigned)f2bf(h1.w) << 16);
        ((uint4*)hb)[(size_t)r * 16 + q] = pk;        // 16B/lane coalesced
        float4 w10 = *(const float4*)(w + q * 8);
        float4 w11 = *(const float4*)(w + q * 8 + 4);
        float4 w20 = *(const float4*)(w + D + q * 8);
        float4 w21 = *(const float4*)(w + D + q * 8 + 4);
        float a1 = h0.x * w10.x + h0.y * w10.y + h0.z * w10.z + h0.w * w10.w
                 + h1.x * w11.x + h1.y * w11.y + h1.z * w11.z + h1.w * w11.w;
        float a2 = h0.x * w20.x + h0.y * w20.y + h0.z * w20.z + h0.w * w20.w
                 + h1.x * w21.x + h1.y * w21.y + h1.z * w21.z + h1.w * w21.w;
        #pragma unroll
        for (int o = 8; o; o >>= 1) { a1 += __shfl_xor(a1, o, 16); a2 += __shfl_xor(a2, o, 16); }
        if (q == 0) { s1[r] = a1; s2[r] = a2; }
    } else if (wv < NODE_WAVES + REL_WAVES) {
        int r = (wv - NODE_WAVES) * 4 + sub;          // 460 = 115*4 exact
        const float* rp = emb_rel + (size_t)r * D + q * 8;
        float4 r0 = *(const float4*)rp;
        float4 r1 = *(const float4*)(rp + 4);
        float4 w30 = *(const float4*)(w + 2 * D + q * 8);
        float4 w31 = *(const float4*)(w + 2 * D + q * 8 + 4);
        float a3 = r0.x * w30.x + r0.y * w30.y + r0.z * w30.z + r0.w * w30.w
                 + r1.x * w31.x + r1.y * w31.y + r1.z * w31.z + r1.w * w31.w;
        #pragma unroll
        for (int o = 8; o; o >>= 1) a3 += __shfl_xor(a3, o, 16);
        if (q == 0) s3[r] = a3;
    }
}

// ---------- scan1: per-block inclusive scan; offsets[i+1]=incl(i), bsums[b]=sum ----------
__global__ void k_scan1(const int* __restrict__ counts, int* __restrict__ offsets,
                        int* __restrict__ bsums) {
    __shared__ int s[256];
    int i = blockIdx.x * 256 + threadIdx.x;
    int v = (i < N_NODES) ? counts[i] : 0;
    s[threadIdx.x] = v;
    __syncthreads();
    for (int off = 1; off < 256; off <<= 1) {
        int t = (threadIdx.x >= off) ? s[threadIdx.x - off] : 0;
        __syncthreads();
        s[threadIdx.x] += t;
        __syncthreads();
    }
    if (i < N_NODES) offsets[i + 1] = s[threadIdx.x];
    if (blockIdx.x == 0 && threadIdx.x == 0) offsets[0] = 0;
    if (threadIdx.x == 255) bsums[blockIdx.x] = s[255];
}

// ---------- scan2: inclusive scan of block sums (196 <= 256) ----------
__global__ void k_scan2(int* __restrict__ bsums, int nb) {
    __shared__ int s[256];
    int t = threadIdx.x;
    s[t] = (t < nb) ? bsums[t] : 0;
    __syncthreads();
    for (int off = 1; off < 256; off <<= 1) {
        int v = (t >= off) ? s[t - off] : 0;
        __syncthreads();
        s[t] += v;
        __syncthreads();
    }
    if (t < nb) bsums[t] = s[t];
}

// global exclusive offset of node d
__device__ __forceinline__ int g_off(const int* offsets, const int* bsums, int d) {
    int blk = d >> 8;
    int base = blk ? bsums[blk - 1] : 0;
    return ((d & 255) ? offsets[d] : 0) + base;
}

// ---------- K3: fused {CSR permutation fill} + {LDS-free MFMA self-loop GEMM} ----------
// CSR entry: src(16b) | typ(16b). No expf, no float gathers in fill phase.
__global__ __launch_bounds__(256) void k_fill_gemm(
        const int* __restrict__ src, const int* __restrict__ dst,
        const int* __restrict__ typ, const int* __restrict__ rank,
        const int* __restrict__ offsets, const int* __restrict__ bsums,
        unsigned* __restrict__ csr,
        const u16* __restrict__ hb, const u16* __restrict__ wt,
        float* __restrict__ out) {
    if (blockIdx.x < FILL_BLOCKS) {
        int i = blockIdx.x * blockDim.x + threadIdx.x;   // 2 edges/thread
        if (i >= N_EDGES / 2) return;
        int2 d2 = ((const int2*)dst)[i];
        int2 s2v = ((const int2*)src)[i];
        int2 t2 = ((const int2*)typ)[i];
        int2 r2 = ((const int2*)rank)[i];
        int slot0 = g_off(offsets, bsums, d2.x) + r2.x;
        int slot1 = g_off(offsets, bsums, d2.y) + r2.y;
        csr[slot0] = (unsigned)s2v.x | ((unsigned)t2.x << 16);
        csr[slot1] = (unsigned)s2v.y | ((unsigned)t2.y << 16);
    } else {
        int b = blockIdx.x - FILL_BLOCKS;
        int t = threadIdx.x;
        int wave = t >> 6, lane = t & 63;
        int quad = lane >> 4, m16 = lane & 15;
        int nbase = b * 64 + wave * 16;

        f32x4 acc[8];
        #pragma unroll
        for (int cg = 0; cg < 8; ++cg) acc[cg] = (f32x4){0.f, 0.f, 0.f, 0.f};

        int arow = nbase + m16;
        if (arow >= N_NODES) arow = N_NODES - 1;         // clamp; stores guarded
        const u16* aptr = hb + (size_t)arow * D + quad * 8;

        #pragma unroll
        for (int k0 = 0; k0 < D; k0 += 32) {
            bf16x8 a = *(const bf16x8*)(aptr + k0);
            #pragma unroll
            for (int cg = 0; cg < 8; ++cg) {
                bf16x8 bb = *(const bf16x8*)(&wt[(size_t)(cg * 16 + m16) * D + k0 + quad * 8]);
                acc[cg] = __builtin_amdgcn_mfma_f32_16x16x32_bf16(a, bb, acc[cg], 0, 0, 0);
            }
        }
        #pragma unroll
        for (int reg = 0; reg < 4; ++reg) {
            int row = nbase + quad * 4 + reg;
            if (row < N_NODES) {
                #pragma unroll
                for (int cg = 0; cg < 8; ++cg)
                    out[(size_t)row * D + cg * 16 + m16] = acc[cg][reg];
            }
        }
    }
}

// ---------- K4: single-pass gather — on-the-fly exp, normalize at end ----------
// out[n] += (sum_e ex_e * h_src) / (sum_e ex_e); 16-lane group per node.
__global__ void k_gather(const u16* __restrict__ hb, const int* __restrict__ offsets,
                         const int* __restrict__ bsums, const unsigned* __restrict__ csr,
                         const float* __restrict__ s1, const float* __restrict__ s2,
                         const float* __restrict__ s3, float* __restrict__ out) {
    int n  = (blockIdx.x * blockDim.x + threadIdx.x) >> 4;
    int gl = threadIdx.x & 15;
    if (n >= N_NODES) return;
    int blk = n >> 8;
    int base = blk ? bsums[blk - 1] : 0;
    int beg = ((n & 255) ? offsets[n] : 0) + base;
    int end = offsets[n + 1] + base;
    if (beg == end) return;                              // deg 0: out = h@W only

    float s2n = s2[n];
    float den = 0.f;
    f32x4 accA = {0.f, 0.f, 0.f, 0.f}, accB = {0.f, 0.f, 0.f, 0.f};

    for (int cb = beg; cb < end; cb += 16) {
        int i = cb + gl;
        int msrc = 0; float mex = 0.f;
        if (i < end) {
            unsigned p = csr[i];
            msrc = (int)(p & 0xFFFFu);
            float x = s1[msrc] + s2n + s3[p >> 16];
            float lv = (x > 0.f) ? x : 0.01f * x;
            mex = __expf(lv);                            // |x| small; shift-invariant
        }
        den += mex;                                      // lane-local; reduced at end
        int cnt = min(16, end - cb);
        int j = 0;
        for (; j + 3 < cnt; j += 4) {
            int   a0 = __shfl(msrc, j, 16),     a1 = __shfl(msrc, j + 1, 16);
            int   a2 = __shfl(msrc, j + 2, 16), a3 = __shfl(msrc, j + 3, 16);
            float c0 = __shfl(mex, j, 16),      c1 = __shfl(mex, j + 1, 16);
            float c2 = __shfl(mex, j + 2, 16),  c3 = __shfl(mex, j + 3, 16);
            uint4 u0 = ((const uint4*)(hb + (size_t)a0 * D))[gl];
            uint4 u1 = ((const uint4*)(hb + (size_t)a1 * D))[gl];
            uint4 u2 = ((const uint4*)(hb + (size_t)a2 * D))[gl];
            uint4 u3 = ((const uint4*)(hb + (size_t)a3 * D))[gl];
            accA.x += c0 * __uint_as_float(u0.x << 16) + c1 * __uint_as_float(u1.x << 16)
                    + c2 * __uint_as_float(u2.x << 16) + c3 * __uint_as_float(u3.x << 16);
            accA.y += c0 * __uint_as_float(u0.x & 0xFFFF0000u) + c1 * __uint_as_float(u1.x & 0xFFFF0000u)
                    + c2 * __uint_as_float(u2.x & 0xFFFF0000u) + c3 * __uint_as_float(u3.x & 0xFFFF0000u);
            accA.z += c0 * __uint_as_float(u0.y << 16) + c1 * __uint_as_float(u1.y << 16)
                    + c2 * __uint_as_float(u2.y << 16) + c3 * __uint_as_float(u3.y << 16);
            accA.w += c0 * __uint_as_float(u0.y & 0xFFFF0000u) + c1 * __uint_as_float(u1.y & 0xFFFF0000u)
                    + c2 * __uint_as_float(u2.y & 0xFFFF0000u) + c3 * __uint_as_float(u3.y & 0xFFFF0000u);
            accB.x += c0 * __uint_as_float(u0.z << 16) + c1 * __uint_as_float(u1.z << 16)
                    + c2 * __uint_as_float(u2.z << 16) + c3 * __uint_as_float(u3.z << 16);
            accB.y += c0 * __uint_as_float(u0.z & 0xFFFF0000u) + c1 * __uint_as_float(u1.z & 0xFFFF0000u)
                    + c2 * __uint_as_float(u2.z & 0xFFFF0000u) + c3 * __uint_as_float(u3.z & 0xFFFF0000u);
            accB.z += c0 * __uint_as_float(u0.w << 16) + c1 * __uint_as_float(u1.w << 16)
                    + c2 * __uint_as_float(u2.w << 16) + c3 * __uint_as_float(u3.w << 16);
            accB.w += c0 * __uint_as_float(u0.w & 0xFFFF0000u) + c1 * __uint_as_float(u1.w & 0xFFFF0000u)
                    + c2 * __uint_as_float(u2.w & 0xFFFF0000u) + c3 * __uint_as_float(u3.w & 0xFFFF0000u);
        }
        for (; j < cnt; ++j) {
            int   a0 = __shfl(msrc, j, 16);
            float c0 = __shfl(mex, j, 16);
            uint4 u0 = ((const uint4*)(hb + (size_t)a0 * D))[gl];
            accA.x += c0 * __uint_as_float(u0.x << 16);
            accA.y += c0 * __uint_as_float(u0.x & 0xFFFF0000u);
            accA.z += c0 * __uint_as_float(u0.y << 16);
            accA.w += c0 * __uint_as_float(u0.y & 0xFFFF0000u);
            accB.x += c0 * __uint_as_float(u0.z << 16);
            accB.y += c0 * __uint_as_float(u0.z & 0xFFFF0000u);
            accB.z += c0 * __uint_as_float(u0.w << 16);
            accB.w += c0 * __uint_as_float(u0.w & 0xFFFF0000u);
        }
    }
    #pragma unroll
    for (int o = 8; o; o >>= 1) den += __shfl_xor(den, o, 16);
    float inv = 1.f / den;

    float* op = out + (size_t)n * D + gl * 8;
    float4 o0 = *(float4*)op, o1 = *(float4*)(op + 4);
    o0.x += accA.x * inv; o0.y += accA.y * inv; o0.z += accA.z * inv; o0.w += accA.w * inv;
    o1.x += accB.x * inv; o1.y += accB.y * inv; o1.z += accB.z * inv; o1.w += accB.w * inv;
    *(float4*)op = o0; *(float4*)(op + 4) = o1;
}

extern "C" void kernel_launch(void* const* d_in, const int* in_sizes, int n_in,
                              void* d_out, int out_size, void* d_ws, size_t ws_size,
                              hipStream_t stream) {
    const float* h       = (const float*)d_in[0];
    const float* emb_rel = (const float*)d_in[1];
    const float* fc1     = (const float*)d_in[2];   // [D, 3D]
    const float* fc2     = (const float*)d_in[3];   // [1, D]
    const float* loopw   = (const float*)d_in[4];   // [D, D]
    const int*   esrc    = (const int*)d_in[5];
    const int*   edst    = (const int*)d_in[6];
    const int*   etyp    = (const int*)d_in[7];
    float* out = (float*)d_out;
    float* ws  = (float*)d_ws;

    float*    w       = ws + OFF_W;
    float*    s1      = ws + OFF_S1;
    float*    s2      = ws + OFF_S2;
    float*    s3      = ws + OFF_S3;
    int*      counts  = (int*)(ws + OFF_COUNTS);
    int*      offsets = (int*)(ws + OFF_OFFSETS);
    int*      bsums   = (int*)(ws + OFF_BSUMS);
    int*      rank    = (int*)(ws + OFF_RANK);
    unsigned* csr     = (unsigned*)(ws + OFF_CSR);
    u16*      hb      = (u16*)(ws + OFF_HB);
    u16*      wt      = (u16*)(ws + OFF_WT);

    // 1: w + Wt^T bf16 + zero counts
    k_prep<<<1 + 64 + ZERO_BLOCKS, 256, 0, stream>>>(fc1, fc2, loopw, w, wt, counts);

    // 2: histogram + rank (counts L2-resident)
    k_count<<<CNT_BLOCKS, 256, 0, stream>>>(edst, counts, rank);

    // 3: node scores + bf16 cast (pure streaming)
    k_scores_cast<<<SCORE_BLOCKS, 256, 0, stream>>>(h, emb_rel, w, s1, s2, s3, hb);

    // 4,5: two-level scan (base-add folded into consumers)
    k_scan1<<<ZERO_BLOCKS, 256, 0, stream>>>(counts, offsets, bsums);
    k_scan2<<<1, 256, 0, stream>>>(bsums, ZERO_BLOCKS);

    // 6: CSR permutation fill overlapped with MFMA self-loop GEMM
    k_fill_gemm<<<FILL_BLOCKS + GEMM_BLOCKS, 256, 0, stream>>>(
        esrc, edst, etyp, rank, offsets, bsums, csr, hb, wt, out);

    // 7: single-pass softmax gather (RMW out)
    k_gather<<<(N_NODES * 16 + 255) / 256, 256, 0, stream>>>(
        hb, offsets, bsums, csr, s1, s2, s3, out);
}

// Round 9
// 192.098 us; speedup vs baseline: 1.0603x; 1.0222x over previous
//
#include <hip/hip_runtime.h>

#define N_NODES 50000
#define N_EDGES 600000
#define D 128
#define N_RELS 460
#define CAP_LOG 6            // 64 CSR slots per node (max degree ~30 for Poisson(12))

typedef unsigned short u16;
typedef __attribute__((ext_vector_type(8))) short bf16x8;   // 8 bf16 (4 VGPRs)
typedef __attribute__((ext_vector_type(4))) float f32x4;

// workspace layout (element offsets, 4-byte elements)
enum : int {
    OFF_W      = 0,          //   384 floats  (w = fc1^T @ fc2^T, split w1|w2|w3)
    OFF_S1     = 384,        // 50000 floats
    OFF_S2     = 50384,      // 50000 floats
    OFF_S3     = 100384,     //   460 floats + pad
    OFF_COUNTS = 100864,     // 50000 ints  (in-degree)
    OFF_RANK   = 150864,     // 600000 ints (edge -> rank within its dst)
    OFF_CSR    = 750864,     // 50000*64 uints (padded CSR: src(16b) | typ(16b))
    OFF_HB     = 3950864,    // 6400000 bf16 = 3200000 float slots (h in bf16)
    OFF_WT     = 7150864,    // 16384 bf16 = 8192 float slots (loop_weight^T bf16)
};                           // total ~27.3 MiB

#define NODE_WAVES   12500   // 4 rows per wave
#define REL_WAVES    115     // 460 rels, 4 per wave
#define SCORE_BLOCKS 3154    // ceil((NODE_WAVES+REL_WAVES)/4)
#define CNT_BLOCKS   586     // ceil(150000/256): 4 edges per thread
#define ZERO_BLOCKS  196     // ceil(50000/256)
#define FILL_BLOCKS  1172    // ceil(300000/256): 2 edges per thread
#define GEMM_BLOCKS  782     // ceil(50000/64)

__device__ __forceinline__ u16 f2bf(float f) {
    unsigned u = __float_as_uint(f);
    unsigned r = u + 0x7FFFu + ((u >> 16) & 1u);   // RNE
    return (u16)(r >> 16);
}

// ---------- K0: fused prep — w vector, Wt bf16 transpose, zero counts ----------
__global__ void k_prep(const float* __restrict__ fc1, const float* __restrict__ fc2,
                       const float* __restrict__ W,
                       float* __restrict__ w, u16* __restrict__ wt,
                       int* __restrict__ counts) {
    int b = blockIdx.x, t = threadIdx.x;
    if (b == 0) {
        for (int j = t; j < 3 * D; j += 256) {
            float acc = 0.f;
            for (int k = 0; k < D; ++k) acc += fc2[k] * fc1[k * 3 * D + j];
            w[j] = acc;
        }
    } else if (b <= 64) {
        int i = (b - 1) * 256 + t;                 // 16384 elems
        int k = i >> 7, n = i & 127;
        wt[n * D + k] = f2bf(W[k * D + n]);
    } else {
        int i = (b - 65) * 256 + t;                // zero 50000 ints
        if (i < N_NODES) counts[i] = 0;
    }
}

// ---------- K1: edge histogram + rank (counts stays L2-hot) ----------
__global__ void k_count(const int* __restrict__ dst, int* __restrict__ counts,
                        int* __restrict__ rank) {
    int i = blockIdx.x * blockDim.x + threadIdx.x;     // 4 edges/thread, int4
    if (i < N_EDGES / 4) {
        int4 d4 = ((const int4*)dst)[i];
        int4 r4;
        r4.x = atomicAdd(&counts[d4.x], 1);
        r4.y = atomicAdd(&counts[d4.y], 1);
        r4.z = atomicAdd(&counts[d4.z], 1);
        r4.w = atomicAdd(&counts[d4.w], 1);
        ((int4*)rank)[i] = r4;                         // coalesced
    }
}

// ---------- K2: 3-way fused {padded-CSR fill} + {MFMA self-loop GEMM} + {scores+cast} ----------
// fill:  csr[dst<<6 | rank] = src | typ<<16  (scattered 4B store, no scan/offsets)
// gemm:  out = h @ loop_weight via bf16 MFMA, reading fp32 h with inline bf16 convert
//        A-frag: A[m=lane&15][k=quad*8+j]; B-frag: B[k=quad*8+j][n=lane&15];
//        C/D: D[m=quad*4+reg][n=lane&15]. Wt[n][k] row-major -> B loads contiguous 16B.
// scores: s1/s2 per node (4 rows/wave) + bf16 cast of h; s3 per relation.
__global__ __launch_bounds__(256) void k_fused(
        const int* __restrict__ src, const int* __restrict__ dst,
        const int* __restrict__ typ, const int* __restrict__ rank,
        unsigned* __restrict__ csr,
        const float* __restrict__ h, const float* __restrict__ emb_rel,
        const float* __restrict__ w,
        float* __restrict__ s1, float* __restrict__ s2, float* __restrict__ s3,
        u16* __restrict__ hb, const u16* __restrict__ wt,
        float* __restrict__ out) {
    if (blockIdx.x < FILL_BLOCKS) {
        // ---- CSR permutation fill: 2 edges/thread ----
        int i = blockIdx.x * blockDim.x + threadIdx.x;
        if (i >= N_EDGES / 2) return;
        int2 d2  = ((const int2*)dst)[i];
        int2 s2v = ((const int2*)src)[i];
        int2 t2  = ((const int2*)typ)[i];
        int2 r2  = ((const int2*)rank)[i];
        csr[(d2.x << CAP_LOG) + r2.x] = (unsigned)s2v.x | ((unsigned)t2.x << 16);
        csr[(d2.y << CAP_LOG) + r2.y] = (unsigned)s2v.y | ((unsigned)t2.y << 16);
    } else if (blockIdx.x < FILL_BLOCKS + GEMM_BLOCKS) {
        // ---- self-loop GEMM (reads fp32 h, inline bf16 convert) ----
        int b = blockIdx.x - FILL_BLOCKS;
        int t = threadIdx.x;
        int wave = t >> 6, lane = t & 63;
        int quad = lane >> 4, m16 = lane & 15;
        int nbase = b * 64 + wave * 16;

        f32x4 acc[8];
        #pragma unroll
        for (int cg = 0; cg < 8; ++cg) acc[cg] = (f32x4){0.f, 0.f, 0.f, 0.f};

        int arow = nbase + m16;
        if (arow >= N_NODES) arow = N_NODES - 1;         // clamp; stores guarded
        const float* aptr = h + (size_t)arow * D + quad * 8;

        #pragma unroll
        for (int k0 = 0; k0 < D; k0 += 32) {
            float4 a0 = *(const float4*)(aptr + k0);
            float4 a1 = *(const float4*)(aptr + k0 + 4);
            bf16x8 a;
            a[0] = (short)f2bf(a0.x); a[1] = (short)f2bf(a0.y);
            a[2] = (short)f2bf(a0.z); a[3] = (short)f2bf(a0.w);
            a[4] = (short)f2bf(a1.x); a[5] = (short)f2bf(a1.y);
            a[6] = (short)f2bf(a1.z); a[7] = (short)f2bf(a1.w);
            #pragma unroll
            for (int cg = 0; cg < 8; ++cg) {
                bf16x8 bb = *(const bf16x8*)(&wt[(size_t)(cg * 16 + m16) * D + k0 + quad * 8]);
                acc[cg] = __builtin_amdgcn_mfma_f32_16x16x32_bf16(a, bb, acc[cg], 0, 0, 0);
            }
        }
        #pragma unroll
        for (int reg = 0; reg < 4; ++reg) {
            int row = nbase + quad * 4 + reg;
            if (row < N_NODES) {
                #pragma unroll
                for (int cg = 0; cg < 8; ++cg)
                    out[(size_t)row * D + cg * 16 + m16] = acc[cg][reg];
            }
        }
    } else {
        // ---- node scores (4 rows/wave) + bf16 cast; rel s3 ----
        int wv = ((blockIdx.x - FILL_BLOCKS - GEMM_BLOCKS) * blockDim.x + threadIdx.x) >> 6;
        int l  = threadIdx.x & 63;
        int sub = l >> 4;                     // which of the wave's 4 rows
        int q   = l & 15;                     // 16 lanes x 8 floats = 128 floats/row
        if (wv < NODE_WAVES) {
            int r = wv * 4 + sub;
            const float* hp = h + (size_t)r * D + q * 8;
            float4 h0 = *(const float4*)hp;
            float4 h1 = *(const float4*)(hp + 4);
            uint4 pk;
            pk.x = (unsigned)f2bf(h0.x) | ((unsigned)f2bf(h0.y) << 16);
            pk.y = (unsigned)f2bf(h0.z) | ((unsigned)f2bf(h0.w) << 16);
            pk.z = (unsigned)f2bf(h1.x) | ((unsigned)f2bf(h1.y) << 16);
            pk.w = (unsigned)f2bf(h1.z) | ((unsigned)f2bf(h1.w) << 16);
            ((uint4*)hb)[(size_t)r * 16 + q] = pk;        // 16B/lane coalesced
            float4 w10 = *(const float4*)(w + q * 8);
            float4 w11 = *(const float4*)(w + q * 8 + 4);
            float4 w20 = *(const float4*)(w + D + q * 8);
            float4 w21 = *(const float4*)(w + D + q * 8 + 4);
            float a1 = h0.x * w10.x + h0.y * w10.y + h0.z * w10.z + h0.w * w10.w
                     + h1.x * w11.x + h1.y * w11.y + h1.z * w11.z + h1.w * w11.w;
            float a2 = h0.x * w20.x + h0.y * w20.y + h0.z * w20.z + h0.w * w20.w
                     + h1.x * w21.x + h1.y * w21.y + h1.z * w21.z + h1.w * w21.w;
            #pragma unroll
            for (int o = 8; o; o >>= 1) { a1 += __shfl_xor(a1, o, 16); a2 += __shfl_xor(a2, o, 16); }
            if (q == 0) { s1[r] = a1; s2[r] = a2; }
        } else if (wv < NODE_WAVES + REL_WAVES) {
            int r = (wv - NODE_WAVES) * 4 + sub;          // 460 = 115*4 exact
            const float* rp = emb_rel + (size_t)r * D + q * 8;
            float4 r0 = *(const float4*)rp;
            float4 r1 = *(const float4*)(rp + 4);
            float4 w30 = *(const float4*)(w + 2 * D + q * 8);
            float4 w31 = *(const float4*)(w + 2 * D + q * 8 + 4);
            float a3 = r0.x * w30.x + r0.y * w30.y + r0.z * w30.z + r0.w * w30.w
                     + r1.x * w31.x + r1.y * w31.y + r1.z * w31.z + r1.w * w31.w;
            #pragma unroll
            for (int o = 8; o; o >>= 1) a3 += __shfl_xor(a3, o, 16);
            if (q == 0) s3[r] = a3;
        }
    }
}

// ---------- K3: single-pass gather — on-the-fly exp, normalize at end ----------
// out[n] += (sum_e ex_e * h_src) / (sum_e ex_e); 16-lane group per node.
__global__ void k_gather(const u16* __restrict__ hb, const int* __restrict__ counts,
                         const unsigned* __restrict__ csr,
                         const float* __restrict__ s1, const float* __restrict__ s2,
                         const float* __restrict__ s3, float* __restrict__ out) {
    int n  = (blockIdx.x * blockDim.x + threadIdx.x) >> 4;
    int gl = threadIdx.x & 15;
    if (n >= N_NODES) return;
    int deg = counts[n];
    if (deg == 0) return;                                // deg 0: out = h@W only
    int beg = n << CAP_LOG;
    int end = beg + deg;

    float s2n = s2[n];
    float den = 0.f;
    f32x4 accA = {0.f, 0.f, 0.f, 0.f}, accB = {0.f, 0.f, 0.f, 0.f};

    for (int cb = beg; cb < end; cb += 16) {
        int i = cb + gl;
        int msrc = 0; float mex = 0.f;
        if (i < end) {
            unsigned p = csr[i];
            msrc = (int)(p & 0xFFFFu);
            float x = s1[msrc] + s2n + s3[p >> 16];
            float lv = (x > 0.f) ? x : 0.01f * x;
            mex = __expf(lv);                            // |x| small; shift-invariant
        }
        den += mex;                                      // lane-local; reduced at end
        int cnt = min(16, end - cb);
        int j = 0;
        for (; j + 3 < cnt; j += 4) {
            int   a0 = __shfl(msrc, j, 16),     a1 = __shfl(msrc, j + 1, 16);
            int   a2 = __shfl(msrc, j + 2, 16), a3 = __shfl(msrc, j + 3, 16);
            float c0 = __shfl(mex, j, 16),      c1 = __shfl(mex, j + 1, 16);
            float c2 = __shfl(mex, j + 2, 16),  c3 = __shfl(mex, j + 3, 16);
            uint4 u0 = ((const uint4*)(hb + (size_t)a0 * D))[gl];
            uint4 u1 = ((const uint4*)(hb + (size_t)a1 * D))[gl];
            uint4 u2 = ((const uint4*)(hb + (size_t)a2 * D))[gl];
            uint4 u3 = ((const uint4*)(hb + (size_t)a3 * D))[gl];
            accA.x += c0 * __uint_as_float(u0.x << 16) + c1 * __uint_as_float(u1.x << 16)
                    + c2 * __uint_as_float(u2.x << 16) + c3 * __uint_as_float(u3.x << 16);
            accA.y += c0 * __uint_as_float(u0.x & 0xFFFF0000u) + c1 * __uint_as_float(u1.x & 0xFFFF0000u)
                    + c2 * __uint_as_float(u2.x & 0xFFFF0000u) + c3 * __uint_as_float(u3.x & 0xFFFF0000u);
            accA.z += c0 * __uint_as_float(u0.y << 16) + c1 * __uint_as_float(u1.y << 16)
                    + c2 * __uint_as_float(u2.y << 16) + c3 * __uint_as_float(u3.y << 16);
            accA.w += c0 * __uint_as_float(u0.y & 0xFFFF0000u) + c1 * __uint_as_float(u1.y & 0xFFFF0000u)
                    + c2 * __uint_as_float(u2.y & 0xFFFF0000u) + c3 * __uint_as_float(u3.y & 0xFFFF0000u);
            accB.x += c0 * __uint_as_float(u0.z << 16) + c1 * __uint_as_float(u1.z << 16)
                    + c2 * __uint_as_float(u2.z << 16) + c3 * __uint_as_float(u3.z << 16);
            accB.y += c0 * __uint_as_float(u0.z & 0xFFFF0000u) + c1 * __uint_as_float(u1.z & 0xFFFF0000u)
                    + c2 * __uint_as_float(u2.z & 0xFFFF0000u) + c3 * __uint_as_float(u3.z & 0xFFFF0000u);
            accB.z += c0 * __uint_as_float(u0.w << 16) + c1 * __uint_as_float(u1.w << 16)
                    + c2 * __uint_as_float(u2.w << 16) + c3 * __uint_as_float(u3.w << 16);
            accB.w += c0 * __uint_as_float(u0.w & 0xFFFF0000u) + c1 * __uint_as_float(u1.w & 0xFFFF0000u)
                    + c2 * __uint_as_float(u2.w & 0xFFFF0000u) + c3 * __uint_as_float(u3.w & 0xFFFF0000u);
        }
        for (; j < cnt; ++j) {
            int   a0 = __shfl(msrc, j, 16);
            float c0 = __shfl(mex, j, 16);
            uint4 u0 = ((const uint4*)(hb + (size_t)a0 * D))[gl];
            accA.x += c0 * __uint_as_float(u0.x << 16);
            accA.y += c0 * __uint_as_float(u0.x & 0xFFFF0000u);
            accA.z += c0 * __uint_as_float(u0.y << 16);
            accA.w += c0 * __uint_as_float(u0.y & 0xFFFF0000u);
            accB.x += c0 * __uint_as_float(u0.z << 16);
            accB.y += c0 * __uint_as_float(u0.z & 0xFFFF0000u);
            accB.z += c0 * __uint_as_float(u0.w << 16);
            accB.w += c0 * __uint_as_float(u0.w & 0xFFFF0000u);
        }
    }
    #pragma unroll
    for (int o = 8; o; o >>= 1) den += __shfl_xor(den, o, 16);
    float inv = 1.f / den;

    float* op = out + (size_t)n * D + gl * 8;
    float4 o0 = *(float4*)op, o1 = *(float4*)(op + 4);
    o0.x += accA.x * inv; o0.y += accA.y * inv; o0.z += accA.z * inv; o0.w += accA.w * inv;
    o1.x += accB.x * inv; o1.y += accB.y * inv; o1.z += accB.z * inv; o1.w += accB.w * inv;
    *(float4*)op = o0; *(float4*)(op + 4) = o1;
}

extern "C" void kernel_launch(void* const* d_in, const int* in_sizes, int n_in,
                              void* d_out, int out_size, void* d_ws, size_t ws_size,
                              hipStream_t stream) {
    const float* h       = (const float*)d_in[0];
    const float* emb_rel = (const float*)d_in[1];
    const float* fc1     = (const float*)d_in[2];   // [D, 3D]
    const float* fc2     = (const float*)d_in[3];   // [1, D]
    const float* loopw   = (const float*)d_in[4];   // [D, D]
    const int*   esrc    = (const int*)d_in[5];
    const int*   edst    = (const int*)d_in[6];
    const int*   etyp    = (const int*)d_in[7];
    float* out = (float*)d_out;
    float* ws  = (float*)d_ws;

    float*    w       = ws + OFF_W;
    float*    s1      = ws + OFF_S1;
    float*    s2      = ws + OFF_S2;
    float*    s3      = ws + OFF_S3;
    int*      counts  = (int*)(ws + OFF_COUNTS);
    int*      rank    = (int*)(ws + OFF_RANK);
    unsigned* csr     = (unsigned*)(ws + OFF_CSR);
    u16*      hb      = (u16*)(ws + OFF_HB);
    u16*      wt      = (u16*)(ws + OFF_WT);

    // 1: w + Wt^T bf16 + zero counts
    k_prep<<<1 + 64 + ZERO_BLOCKS, 256, 0, stream>>>(fc1, fc2, loopw, w, wt, counts);

    // 2: histogram + rank (counts L2-resident)
    k_count<<<CNT_BLOCKS, 256, 0, stream>>>(edst, counts, rank);

    // 3: fused CSR fill (scattered) + MFMA GEMM (matrix pipe) + scores/cast (streaming)
    k_fused<<<FILL_BLOCKS + GEMM_BLOCKS + SCORE_BLOCKS, 256, 0, stream>>>(
        esrc, edst, etyp, rank, csr, h, emb_rel, w, s1, s2, s3, hb, wt, out);

    // 4: single-pass softmax gather (RMW out)
    k_gather<<<(N_NODES * 16 + 255) / 256, 256, 0, stream>>>(
        hb, counts, csr, s1, s2, s3, out);
}

// Round 10
// 173.770 us; speedup vs baseline: 1.1722x; 1.1055x over previous
//
#include <hip/hip_runtime.h>

#define N_NODES 50000
#define N_EDGES 600000
#define D 128
#define N_RELS 460
#define CAP_LOG 6            // 64 CSR slots per node (max degree ~35 for Poisson(12))

typedef unsigned short u16;
typedef __attribute__((ext_vector_type(8))) short bf16x8;   // 8 bf16 (4 VGPRs)
typedef __attribute__((ext_vector_type(4))) float f32x4;

// workspace layout (element offsets, 4-byte elements)
enum : int {
    OFF_W      = 0,          //   384 floats  (w = fc1^T @ fc2^T, split w1|w2|w3)
    OFF_S1     = 384,        // 50000 floats
    OFF_S2     = 50384,      // 50000 floats
    OFF_S3     = 100384,     //   460 floats + pad
    OFF_COUNTS = 100864,     // 50000*16 ints (one counter per 64B line)
    OFF_CSR    = 900864,     // 50000*64 uints (padded CSR: src(16b) | typ(16b))
    OFF_HB     = 4100864,    // 6400000 bf16 = 3200000 float slots (h in bf16)
    OFF_WT     = 7300864,    // 16384 bf16 = 8192 float slots (loop_weight^T bf16)
};                           // total ~27.9 MiB

#define NODE_WAVES   12500   // 4 rows per wave
#define REL_WAVES    115     // 460 rels, 4 per wave
#define SCORE_BLOCKS 3154    // ceil((NODE_WAVES+REL_WAVES)/4)
#define ZERO_BLOCKS  3125    // ceil(800000/256)
#define FILL_BLOCKS  1172    // ceil(300000/256): 2 edges per thread
#define GEMM_BLOCKS  782     // ceil(50000/64)

__device__ __forceinline__ u16 f2bf(float f) {
    unsigned u = __float_as_uint(f);
    unsigned r = u + 0x7FFFu + ((u >> 16) & 1u);   // RNE
    return (u16)(r >> 16);
}

// ---------- K0: fused prep — w vector, Wt bf16 transpose, zero padded counts ----------
__global__ void k_prep(const float* __restrict__ fc1, const float* __restrict__ fc2,
                       const float* __restrict__ W,
                       float* __restrict__ w, u16* __restrict__ wt,
                       int* __restrict__ counts) {
    int b = blockIdx.x, t = threadIdx.x;
    if (b == 0) {
        for (int j = t; j < 3 * D; j += 256) {
            float acc = 0.f;
            for (int k = 0; k < D; ++k) acc += fc2[k] * fc1[k * 3 * D + j];
            w[j] = acc;
        }
    } else if (b <= 64) {
        int i = (b - 1) * 256 + t;                 // 16384 elems
        int k = i >> 7, n = i & 127;
        wt[n * D + k] = f2bf(W[k * D + n]);
    } else {
        int i = (b - 65) * 256 + t;                // zero 800000 ints (padded counters)
        if (i < N_NODES * 16) counts[i] = 0;
    }
}

// ---------- K1: 3-way fused {atomic CSR fill} + {MFMA self-loop GEMM} + {scores+cast} ----------
// fill:  slot = atomicAdd(&counts[dst*16],1); csr[dst<<6 | slot] = src | typ<<16
//        (line-padded counters: no cross-node same-line atomic serialization)
// gemm:  out = h @ loop_weight via bf16 MFMA, fp32 h with inline bf16 convert
//        A-frag: A[m=lane&15][k=quad*8+j]; B-frag: B[k=quad*8+j][n=lane&15];
//        C/D: D[m=quad*4+reg][n=lane&15]. Wt[n][k] row-major -> B loads contiguous 16B.
// scores: s1/s2 per node (4 rows/wave) + bf16 cast of h; s3 per relation.
__global__ __launch_bounds__(256) void k_fused(
        const int* __restrict__ src, const int* __restrict__ dst,
        const int* __restrict__ typ, int* __restrict__ counts,
        unsigned* __restrict__ csr,
        const float* __restrict__ h, const float* __restrict__ emb_rel,
        const float* __restrict__ w,
        float* __restrict__ s1, float* __restrict__ s2, float* __restrict__ s3,
        u16* __restrict__ hb, const u16* __restrict__ wt,
        float* __restrict__ out) {
    if (blockIdx.x < FILL_BLOCKS) {
        // ---- CSR fill with line-padded atomic rank: 2 edges/thread ----
        int i = blockIdx.x * blockDim.x + threadIdx.x;
        if (i >= N_EDGES / 2) return;
        int2 d2  = ((const int2*)dst)[i];
        int2 s2v = ((const int2*)src)[i];
        int2 t2  = ((const int2*)typ)[i];
        int slot0 = atomicAdd(&counts[d2.x << 4], 1);
        int slot1 = atomicAdd(&counts[d2.y << 4], 1);
        csr[(d2.x << CAP_LOG) + slot0] = (unsigned)s2v.x | ((unsigned)t2.x << 16);
        csr[(d2.y << CAP_LOG) + slot1] = (unsigned)s2v.y | ((unsigned)t2.y << 16);
    } else if (blockIdx.x < FILL_BLOCKS + GEMM_BLOCKS) {
        // ---- self-loop GEMM (reads fp32 h, inline bf16 convert) ----
        int b = blockIdx.x - FILL_BLOCKS;
        int t = threadIdx.x;
        int wave = t >> 6, lane = t & 63;
        int quad = lane >> 4, m16 = lane & 15;
        int nbase = b * 64 + wave * 16;

        f32x4 acc[8];
        #pragma unroll
        for (int cg = 0; cg < 8; ++cg) acc[cg] = (f32x4){0.f, 0.f, 0.f, 0.f};

        int arow = nbase + m16;
        if (arow >= N_NODES) arow = N_NODES - 1;         // clamp; stores guarded
        const float* aptr = h + (size_t)arow * D + quad * 8;

        #pragma unroll
        for (int k0 = 0; k0 < D; k0 += 32) {
            float4 a0 = *(const float4*)(aptr + k0);
            float4 a1 = *(const float4*)(aptr + k0 + 4);
            bf16x8 a;
            a[0] = (short)f2bf(a0.x); a[1] = (short)f2bf(a0.y);
            a[2] = (short)f2bf(a0.z); a[3] = (short)f2bf(a0.w);
            a[4] = (short)f2bf(a1.x); a[5] = (short)f2bf(a1.y);
            a[6] = (short)f2bf(a1.z); a[7] = (short)f2bf(a1.w);
            #pragma unroll
            for (int cg = 0; cg < 8; ++cg) {
                bf16x8 bb = *(const bf16x8*)(&wt[(size_t)(cg * 16 + m16) * D + k0 + quad * 8]);
                acc[cg] = __builtin_amdgcn_mfma_f32_16x16x32_bf16(a, bb, acc[cg], 0, 0, 0);
            }
        }
        #pragma unroll
        for (int reg = 0; reg < 4; ++reg) {
            int row = nbase + quad * 4 + reg;
            if (row < N_NODES) {
                #pragma unroll
                for (int cg = 0; cg < 8; ++cg)
                    out[(size_t)row * D + cg * 16 + m16] = acc[cg][reg];
            }
        }
    } else {
        // ---- node scores (4 rows/wave) + bf16 cast; rel s3 ----
        int wv = ((blockIdx.x - FILL_BLOCKS - GEMM_BLOCKS) * blockDim.x + threadIdx.x) >> 6;
        int l  = threadIdx.x & 63;
        int sub = l >> 4;                     // which of the wave's 4 rows
        int q   = l & 15;                     // 16 lanes x 8 floats = 128 floats/row
        if (wv < NODE_WAVES) {
            int r = wv * 4 + sub;
            const float* hp = h + (size_t)r * D + q * 8;
            float4 h0 = *(const float4*)hp;
            float4 h1 = *(const float4*)(hp + 4);
            uint4 pk;
            pk.x = (unsigned)f2bf(h0.x) | ((unsigned)f2bf(h0.y) << 16);
            pk.y = (unsigned)f2bf(h0.z) | ((unsigned)f2bf(h0.w) << 16);
            pk.z = (unsigned)f2bf(h1.x) | ((unsigned)f2bf(h1.y) << 16);
            pk.w = (unsigned)f2bf(h1.z) | ((unsigned)f2bf(h1.w) << 16);
            ((uint4*)hb)[(size_t)r * 16 + q] = pk;        // 16B/lane coalesced
            float4 w10 = *(const float4*)(w + q * 8);
            float4 w11 = *(const float4*)(w + q * 8 + 4);
            float4 w20 = *(const float4*)(w + D + q * 8);
            float4 w21 = *(const float4*)(w + D + q * 8 + 4);
            float a1 = h0.x * w10.x + h0.y * w10.y + h0.z * w10.z + h0.w * w10.w
                     + h1.x * w11.x + h1.y * w11.y + h1.z * w11.z + h1.w * w11.w;
            float a2 = h0.x * w20.x + h0.y * w20.y + h0.z * w20.z + h0.w * w20.w
                     + h1.x * w21.x + h1.y * w21.y + h1.z * w21.z + h1.w * w21.w;
            #pragma unroll
            for (int o = 8; o; o >>= 1) { a1 += __shfl_xor(a1, o, 16); a2 += __shfl_xor(a2, o, 16); }
            if (q == 0) { s1[r] = a1; s2[r] = a2; }
        } else if (wv < NODE_WAVES + REL_WAVES) {
            int r = (wv - NODE_WAVES) * 4 + sub;          // 460 = 115*4 exact
            const float* rp = emb_rel + (size_t)r * D + q * 8;
            float4 r0 = *(const float4*)rp;
            float4 r1 = *(const float4*)(rp + 4);
            float4 w30 = *(const float4*)(w + 2 * D + q * 8);
            float4 w31 = *(const float4*)(w + 2 * D + q * 8 + 4);
            float a3 = r0.x * w30.x + r0.y * w30.y + r0.z * w30.z + r0.w * w30.w
                     + r1.x * w31.x + r1.y * w31.y + r1.z * w31.z + r1.w * w31.w;
            #pragma unroll
            for (int o = 8; o; o >>= 1) a3 += __shfl_xor(a3, o, 16);
            if (q == 0) s3[r] = a3;
        }
    }
}

// ---------- K2: single-pass gather — on-the-fly exp, normalize at end ----------
// out[n] += (sum_e ex_e * h_src) / (sum_e ex_e); 16-lane group per node.
__global__ void k_gather(const u16* __restrict__ hb, const int* __restrict__ counts,
                         const unsigned* __restrict__ csr,
                         const float* __restrict__ s1, const float* __restrict__ s2,
                         const float* __restrict__ s3, float* __restrict__ out) {
    int n  = (blockIdx.x * blockDim.x + threadIdx.x) >> 4;
    int gl = threadIdx.x & 15;
    if (n >= N_NODES) return;
    int deg = counts[n << 4];
    if (deg == 0) return;                                // deg 0: out = h@W only
    int beg = n << CAP_LOG;
    int end = beg + deg;

    float s2n = s2[n];
    float den = 0.f;
    f32x4 accA = {0.f, 0.f, 0.f, 0.f}, accB = {0.f, 0.f, 0.f, 0.f};

    for (int cb = beg; cb < end; cb += 16) {
        int i = cb + gl;
        int msrc = 0; float mex = 0.f;
        if (i < end) {
            unsigned p = csr[i];
            msrc = (int)(p & 0xFFFFu);
            float x = s1[msrc] + s2n + s3[p >> 16];
            float lv = (x > 0.f) ? x : 0.01f * x;
            mex = __expf(lv);                            // |x| small; shift-invariant
        }
        den += mex;                                      // lane-local; reduced at end
        int cnt = min(16, end - cb);
        int j = 0;
        for (; j + 3 < cnt; j += 4) {
            int   a0 = __shfl(msrc, j, 16),     a1 = __shfl(msrc, j + 1, 16);
            int   a2 = __shfl(msrc, j + 2, 16), a3 = __shfl(msrc, j + 3, 16);
            float c0 = __shfl(mex, j, 16),      c1 = __shfl(mex, j + 1, 16);
            float c2 = __shfl(mex, j + 2, 16),  c3 = __shfl(mex, j + 3, 16);
            uint4 u0 = ((const uint4*)(hb + (size_t)a0 * D))[gl];
            uint4 u1 = ((const uint4*)(hb + (size_t)a1 * D))[gl];
            uint4 u2 = ((const uint4*)(hb + (size_t)a2 * D))[gl];
            uint4 u3 = ((const uint4*)(hb + (size_t)a3 * D))[gl];
            accA.x += c0 * __uint_as_float(u0.x << 16) + c1 * __uint_as_float(u1.x << 16)
                    + c2 * __uint_as_float(u2.x << 16) + c3 * __uint_as_float(u3.x << 16);
            accA.y += c0 * __uint_as_float(u0.x & 0xFFFF0000u) + c1 * __uint_as_float(u1.x & 0xFFFF0000u)
                    + c2 * __uint_as_float(u2.x & 0xFFFF0000u) + c3 * __uint_as_float(u3.x & 0xFFFF0000u);
            accA.z += c0 * __uint_as_float(u0.y << 16) + c1 * __uint_as_float(u1.y << 16)
                    + c2 * __uint_as_float(u2.y << 16) + c3 * __uint_as_float(u3.y << 16);
            accA.w += c0 * __uint_as_float(u0.y & 0xFFFF0000u) + c1 * __uint_as_float(u1.y & 0xFFFF0000u)
                    + c2 * __uint_as_float(u2.y & 0xFFFF0000u) + c3 * __uint_as_float(u3.y & 0xFFFF0000u);
            accB.x += c0 * __uint_as_float(u0.z << 16) + c1 * __uint_as_float(u1.z << 16)
                    + c2 * __uint_as_float(u2.z << 16) + c3 * __uint_as_float(u3.z << 16);
            accB.y += c0 * __uint_as_float(u0.z & 0xFFFF0000u) + c1 * __uint_as_float(u1.z & 0xFFFF0000u)
                    + c2 * __uint_as_float(u2.z & 0xFFFF0000u) + c3 * __uint_as_float(u3.z & 0xFFFF0000u);
            accB.z += c0 * __uint_as_float(u0.w << 16) + c1 * __uint_as_float(u1.w << 16)
                    + c2 * __uint_as_float(u2.w << 16) + c3 * __uint_as_float(u3.w << 16);
            accB.w += c0 * __uint_as_float(u0.w & 0xFFFF0000u) + c1 * __uint_as_float(u1.w & 0xFFFF0000u)
                    + c2 * __uint_as_float(u2.w & 0xFFFF0000u) + c3 * __uint_as_float(u3.w & 0xFFFF0000u);
        }
        for (; j < cnt; ++j) {
            int   a0 = __shfl(msrc, j, 16);
            float c0 = __shfl(mex, j, 16);
            uint4 u0 = ((const uint4*)(hb + (size_t)a0 * D))[gl];
            accA.x += c0 * __uint_as_float(u0.x << 16);
            accA.y += c0 * __uint_as_float(u0.x & 0xFFFF0000u);
            accA.z += c0 * __uint_as_float(u0.y << 16);
            accA.w += c0 * __uint_as_float(u0.y & 0xFFFF0000u);
            accB.x += c0 * __uint_as_float(u0.z << 16);
            accB.y += c0 * __uint_as_float(u0.z & 0xFFFF0000u);
            accB.z += c0 * __uint_as_float(u0.w << 16);
            accB.w += c0 * __uint_as_float(u0.w & 0xFFFF0000u);
        }
    }
    #pragma unroll
    for (int o = 8; o; o >>= 1) den += __shfl_xor(den, o, 16);
    float inv = 1.f / den;

    float* op = out + (size_t)n * D + gl * 8;
    float4 o0 = *(float4*)op, o1 = *(float4*)(op + 4);
    o0.x += accA.x * inv; o0.y += accA.y * inv; o0.z += accA.z * inv; o0.w += accA.w * inv;
    o1.x += accB.x * inv; o1.y += accB.y * inv; o1.z += accB.z * inv; o1.w += accB.w * inv;
    *(float4*)op = o0; *(float4*)(op + 4) = o1;
}

extern "C" void kernel_launch(void* const* d_in, const int* in_sizes, int n_in,
                              void* d_out, int out_size, void* d_ws, size_t ws_size,
                              hipStream_t stream) {
    const float* h       = (const float*)d_in[0];
    const float* emb_rel = (const float*)d_in[1];
    const float* fc1     = (const float*)d_in[2];   // [D, 3D]
    const float* fc2     = (const float*)d_in[3];   // [1, D]
    const float* loopw   = (const float*)d_in[4];   // [D, D]
    const int*   esrc    = (const int*)d_in[5];
    const int*   edst    = (const int*)d_in[6];
    const int*   etyp    = (const int*)d_in[7];
    float* out = (float*)d_out;
    float* ws  = (float*)d_ws;

    float*    w       = ws + OFF_W;
    float*    s1      = ws + OFF_S1;
    float*    s2      = ws + OFF_S2;
    float*    s3      = ws + OFF_S3;
    int*      counts  = (int*)(ws + OFF_COUNTS);
    unsigned* csr     = (unsigned*)(ws + OFF_CSR);
    u16*      hb      = (u16*)(ws + OFF_HB);
    u16*      wt      = (u16*)(ws + OFF_WT);

    // 1: w + Wt^T bf16 + zero line-padded counters
    k_prep<<<1 + 64 + ZERO_BLOCKS, 256, 0, stream>>>(fc1, fc2, loopw, w, wt, counts);

    // 2: fused atomic CSR fill + MFMA GEMM + scores/cast
    k_fused<<<FILL_BLOCKS + GEMM_BLOCKS + SCORE_BLOCKS, 256, 0, stream>>>(
        esrc, edst, etyp, counts, csr, h, emb_rel, w, s1, s2, s3, hb, wt, out);

    // 3: single-pass softmax gather (RMW out)
    k_gather<<<(N_NODES * 16 + 255) / 256, 256, 0, stream>>>(
        hb, counts, csr, s1, s2, s3, out);
}

// Round 11
// 172.229 us; speedup vs baseline: 1.1827x; 1.0089x over previous
//
#include <hip/hip_runtime.h>

#define N_NODES 50000
#define N_EDGES 600000
#define D 128
#define N_RELS 460
#define CAP_LOG 6            // 64 CSR slots per node (max degree ~35 for Poisson(12))

typedef unsigned short u16;
typedef __attribute__((ext_vector_type(8))) short bf16x8;   // 8 bf16 (4 VGPRs)
typedef __attribute__((ext_vector_type(4))) float f32x4;

// workspace layout (element offsets, 4-byte elements)
enum : int {
    OFF_W      = 0,          //   384 floats  (w = fc1^T @ fc2^T, split w1|w2|w3)
    OFF_S1     = 384,        // 50000 floats
    OFF_S2     = 50384,      // 50000 floats
    OFF_S3     = 100384,     //   460 floats + pad
    OFF_COUNTS = 100864,     // 50000*16 ints (one counter per 64B line)
    OFF_CSR    = 900864,     // 50000*64 uints (padded CSR: src(16b) | typ(16b))
    OFF_HB     = 4100864,    // 6400000 bf16 = 3200000 float slots (h in bf16)
};                           // total ~27.9 MiB

#define NODE_WAVES   12500   // 4 rows per wave
#define REL_WAVES    115     // 460 rels, 4 per wave
#define SCORE_BLOCKS 3154    // ceil((NODE_WAVES+REL_WAVES)/4)
#define GEMM_BLOCKS  782     // ceil(50000/64)
#define ZERO_BLOCKS  196     // 196*256 threads * 16 ints >= 800000
#define FILL_BLOCKS  586     // ceil(150000/256): 4 edges per thread
#define WT_STRIDE    136     // LDS row stride (bf16 elems): 272B, 16B-aligned b128

__device__ __forceinline__ u16 f2bf(float f) {
    unsigned u = __float_as_uint(f);
    unsigned r = u + 0x7FFFu + ((u >> 16) & 1u);   // RNE
    return (u16)(r >> 16);
}

// ---------- K0: fused prep — {MFMA self-loop GEMM} + {zero counters} + {w vector} ----------
// gemm: out = h @ loop_weight via bf16 MFMA. W staged fp32->bf16 transposed into LDS
//       (self-contained: no precomputed wt needed).
//       A-frag: A[m=lane&15][k=quad*8+j]; B-frag: B[k=quad*8+j][n=lane&15];
//       C/D: D[m=quad*4+reg][n=lane&15].
__global__ __launch_bounds__(256) void k_prep(
        const float* __restrict__ fc1, const float* __restrict__ fc2,
        const float* __restrict__ W, const float* __restrict__ h,
        float* __restrict__ w, int* __restrict__ counts,
        float* __restrict__ out) {
    __shared__ u16 Ws[D * WT_STRIDE];                   // 34 KiB
    int t = threadIdx.x;
    if (blockIdx.x < GEMM_BLOCKS) {
        // stage W transposed: Ws[n*136 + k] = bf16(W[k][n])
        for (int i = t; i < (D * D) / 4; i += 256) {    // 4096 float4-units
            float4 v = ((const float4*)W)[i];
            int k  = i >> 5;                            // 32 float4 per row
            int n0 = (i & 31) * 4;
            Ws[(n0 + 0) * WT_STRIDE + k] = f2bf(v.x);
            Ws[(n0 + 1) * WT_STRIDE + k] = f2bf(v.y);
            Ws[(n0 + 2) * WT_STRIDE + k] = f2bf(v.z);
            Ws[(n0 + 3) * WT_STRIDE + k] = f2bf(v.w);
        }
        __syncthreads();

        int wave = t >> 6, lane = t & 63;
        int quad = lane >> 4, m16 = lane & 15;
        int nbase = blockIdx.x * 64 + wave * 16;

        f32x4 acc[8];
        #pragma unroll
        for (int cg = 0; cg < 8; ++cg) acc[cg] = (f32x4){0.f, 0.f, 0.f, 0.f};

        int arow = nbase + m16;
        if (arow >= N_NODES) arow = N_NODES - 1;        // clamp; stores guarded
        const float* aptr = h + (size_t)arow * D + quad * 8;

        #pragma unroll
        for (int k0 = 0; k0 < D; k0 += 32) {
            float4 a0 = *(const float4*)(aptr + k0);
            float4 a1 = *(const float4*)(aptr + k0 + 4);
            bf16x8 a;
            a[0] = (short)f2bf(a0.x); a[1] = (short)f2bf(a0.y);
            a[2] = (short)f2bf(a0.z); a[3] = (short)f2bf(a0.w);
            a[4] = (short)f2bf(a1.x); a[5] = (short)f2bf(a1.y);
            a[6] = (short)f2bf(a1.z); a[7] = (short)f2bf(a1.w);
            #pragma unroll
            for (int cg = 0; cg < 8; ++cg) {
                bf16x8 bb = *(const bf16x8*)(&Ws[(cg * 16 + m16) * WT_STRIDE + k0 + quad * 8]);
                acc[cg] = __builtin_amdgcn_mfma_f32_16x16x32_bf16(a, bb, acc[cg], 0, 0, 0);
            }
        }
        #pragma unroll
        for (int reg = 0; reg < 4; ++reg) {
            int row = nbase + quad * 4 + reg;
            if (row < N_NODES) {
                #pragma unroll
                for (int cg = 0; cg < 8; ++cg)
                    out[(size_t)row * D + cg * 16 + m16] = acc[cg][reg];
            }
        }
    } else if (blockIdx.x < GEMM_BLOCKS + ZERO_BLOCKS) {
        // zero 800000 line-padded counters, 16 ints/thread via int4
        int base = ((blockIdx.x - GEMM_BLOCKS) * 256 + t) * 4;   // int4 index *4? no:
        // 196*256 threads * 4 int4 = 802816 int4?? -> use explicit loop of 4 int4 stores
        int i4 = ((blockIdx.x - GEMM_BLOCKS) * 256 + t);
        #pragma unroll
        for (int rep = 0; rep < 4; ++rep) {
            int idx = (i4 * 4 + rep);                   // int4 slot
            if (idx * 4 < N_NODES * 16)
                ((int4*)counts)[idx] = make_int4(0, 0, 0, 0);
        }
        (void)base;
    } else {
        // w[j] = sum_k fc2[k] * fc1[k][j]
        for (int j = t; j < 3 * D; j += 256) {
            float acc = 0.f;
            for (int k = 0; k < D; ++k) acc += fc2[k] * fc1[k * 3 * D + j];
            w[j] = acc;
        }
    }
}

// ---------- K1: fused {atomic CSR fill, 4 edges/thread} + {scores+cast} ----------
__global__ __launch_bounds__(256) void k_fused(
        const int* __restrict__ src, const int* __restrict__ dst,
        const int* __restrict__ typ, int* __restrict__ counts,
        unsigned* __restrict__ csr,
        const float* __restrict__ h, const float* __restrict__ emb_rel,
        const float* __restrict__ w,
        float* __restrict__ s1, float* __restrict__ s2, float* __restrict__ s3,
        u16* __restrict__ hb) {
    if (blockIdx.x < FILL_BLOCKS) {
        // ---- CSR fill with line-padded atomic rank: 4 independent chains/thread ----
        int i = blockIdx.x * blockDim.x + threadIdx.x;
        if (i >= N_EDGES / 4) return;
        int4 d4 = ((const int4*)dst)[i];
        int4 s4 = ((const int4*)src)[i];
        int4 t4 = ((const int4*)typ)[i];
        int sl0 = atomicAdd(&counts[d4.x << 4], 1);
        int sl1 = atomicAdd(&counts[d4.y << 4], 1);
        int sl2 = atomicAdd(&counts[d4.z << 4], 1);
        int sl3 = atomicAdd(&counts[d4.w << 4], 1);
        csr[(d4.x << CAP_LOG) + sl0] = (unsigned)s4.x | ((unsigned)t4.x << 16);
        csr[(d4.y << CAP_LOG) + sl1] = (unsigned)s4.y | ((unsigned)t4.y << 16);
        csr[(d4.z << CAP_LOG) + sl2] = (unsigned)s4.z | ((unsigned)t4.z << 16);
        csr[(d4.w << CAP_LOG) + sl3] = (unsigned)s4.w | ((unsigned)t4.w << 16);
    } else {
        // ---- node scores (4 rows/wave) + bf16 cast; rel s3 ----
        int wv = ((blockIdx.x - FILL_BLOCKS) * blockDim.x + threadIdx.x) >> 6;
        int l  = threadIdx.x & 63;
        int sub = l >> 4;                     // which of the wave's 4 rows
        int q   = l & 15;                     // 16 lanes x 8 floats = 128 floats/row
        if (wv < NODE_WAVES) {
            int r = wv * 4 + sub;
            const float* hp = h + (size_t)r * D + q * 8;
            float4 h0 = *(const float4*)hp;
            float4 h1 = *(const float4*)(hp + 4);
            uint4 pk;
            pk.x = (unsigned)f2bf(h0.x) | ((unsigned)f2bf(h0.y) << 16);
            pk.y = (unsigned)f2bf(h0.z) | ((unsigned)f2bf(h0.w) << 16);
            pk.z = (unsigned)f2bf(h1.x) | ((unsigned)f2bf(h1.y) << 16);
            pk.w = (unsigned)f2bf(h1.z) | ((unsigned)f2bf(h1.w) << 16);
            ((uint4*)hb)[(size_t)r * 16 + q] = pk;        // 16B/lane coalesced
            float4 w10 = *(const float4*)(w + q * 8);
            float4 w11 = *(const float4*)(w + q * 8 + 4);
            float4 w20 = *(const float4*)(w + D + q * 8);
            float4 w21 = *(const float4*)(w + D + q * 8 + 4);
            float a1 = h0.x * w10.x + h0.y * w10.y + h0.z * w10.z + h0.w * w10.w
                     + h1.x * w11.x + h1.y * w11.y + h1.z * w11.z + h1.w * w11.w;
            float a2 = h0.x * w20.x + h0.y * w20.y + h0.z * w20.z + h0.w * w20.w
                     + h1.x * w21.x + h1.y * w21.y + h1.z * w21.z + h1.w * w21.w;
            #pragma unroll
            for (int o = 8; o; o >>= 1) { a1 += __shfl_xor(a1, o, 16); a2 += __shfl_xor(a2, o, 16); }
            if (q == 0) { s1[r] = a1; s2[r] = a2; }
        } else if (wv < NODE_WAVES + REL_WAVES) {
            int r = (wv - NODE_WAVES) * 4 + sub;          // 460 = 115*4 exact
            const float* rp = emb_rel + (size_t)r * D + q * 8;
            float4 r0 = *(const float4*)rp;
            float4 r1 = *(const float4*)(rp + 4);
            float4 w30 = *(const float4*)(w + 2 * D + q * 8);
            float4 w31 = *(const float4*)(w + 2 * D + q * 8 + 4);
            float a3 = r0.x * w30.x + r0.y * w30.y + r0.z * w30.z + r0.w * w30.w
                     + r1.x * w31.x + r1.y * w31.y + r1.z * w31.z + r1.w * w31.w;
            #pragma unroll
            for (int o = 8; o; o >>= 1) a3 += __shfl_xor(a3, o, 16);
            if (q == 0) s3[r] = a3;
        }
    }
}

#define ROWACC(uu, cc)                                                         \
    accA.x += (cc) * __uint_as_float((uu).x << 16);                            \
    accA.y += (cc) * __uint_as_float((uu).x & 0xFFFF0000u);                    \
    accA.z += (cc) * __uint_as_float((uu).y << 16);                            \
    accA.w += (cc) * __uint_as_float((uu).y & 0xFFFF0000u);                    \
    accB.x += (cc) * __uint_as_float((uu).z << 16);                            \
    accB.y += (cc) * __uint_as_float((uu).z & 0xFFFF0000u);                    \
    accB.z += (cc) * __uint_as_float((uu).w << 16);                            \
    accB.w += (cc) * __uint_as_float((uu).w & 0xFFFF0000u);

// ---------- K2: single-pass gather — on-the-fly exp, normalize at end ----------
__global__ void k_gather(const u16* __restrict__ hb, const int* __restrict__ counts,
                         const unsigned* __restrict__ csr,
                         const float* __restrict__ s1, const float* __restrict__ s2,
                         const float* __restrict__ s3, float* __restrict__ out) {
    int n  = (blockIdx.x * blockDim.x + threadIdx.x) >> 4;
    int gl = threadIdx.x & 15;
    if (n >= N_NODES) return;
    int deg = counts[n << 4];
    if (deg == 0) return;                                // deg 0: out = h@W only
    int beg = n << CAP_LOG;
    int end = beg + deg;

    float s2n = s2[n];
    float den = 0.f;
    f32x4 accA = {0.f, 0.f, 0.f, 0.f}, accB = {0.f, 0.f, 0.f, 0.f};

    for (int cb = beg; cb < end; cb += 16) {
        int i = cb + gl;
        int msrc = 0; float mex = 0.f;
        if (i < end) {
            unsigned p = csr[i];
            msrc = (int)(p & 0xFFFFu);
            float x = s1[msrc] + s2n + s3[p >> 16];
            float lv = (x > 0.f) ? x : 0.01f * x;
            mex = __expf(lv);                            // |x| small; shift-invariant
        }
        den += mex;                                      // lane-local; reduced at end
        int cnt = min(16, end - cb);
        int j = 0;
        for (; j + 7 < cnt; j += 8) {                    // 8 loads in flight
            int aa[8]; float cc[8]; uint4 uu[8];
            #pragma unroll
            for (int u = 0; u < 8; ++u) {
                aa[u] = __shfl(msrc, j + u, 16);
                cc[u] = __shfl(mex,  j + u, 16);
            }
            #pragma unroll
            for (int u = 0; u < 8; ++u)
                uu[u] = ((const uint4*)(hb + (size_t)aa[u] * D))[gl];
            #pragma unroll
            for (int u = 0; u < 8; ++u) { ROWACC(uu[u], cc[u]); }
        }
        for (; j + 3 < cnt; j += 4) {
            int aa[4]; float cc[4]; uint4 uu[4];
            #pragma unroll
            for (int u = 0; u < 4; ++u) {
                aa[u] = __shfl(msrc, j + u, 16);
                cc[u] = __shfl(mex,  j + u, 16);
            }
            #pragma unroll
            for (int u = 0; u < 4; ++u)
                uu[u] = ((const uint4*)(hb + (size_t)aa[u] * D))[gl];
            #pragma unroll
            for (int u = 0; u < 4; ++u) { ROWACC(uu[u], cc[u]); }
        }
        for (; j < cnt; ++j) {
            int   a0 = __shfl(msrc, j, 16);
            float c0 = __shfl(mex, j, 16);
            uint4 u0 = ((const uint4*)(hb + (size_t)a0 * D))[gl];
            ROWACC(u0, c0);
        }
    }
    #pragma unroll
    for (int o = 8; o; o >>= 1) den += __shfl_xor(den, o, 16);
    float inv = 1.f / den;

    float* op = out + (size_t)n * D + gl * 8;
    float4 o0 = *(float4*)op, o1 = *(float4*)(op + 4);
    o0.x += accA.x * inv; o0.y += accA.y * inv; o0.z += accA.z * inv; o0.w += accA.w * inv;
    o1.x += accB.x * inv; o1.y += accB.y * inv; o1.z += accB.z * inv; o1.w += accB.w * inv;
    *(float4*)op = o0; *(float4*)(op + 4) = o1;
}

extern "C" void kernel_launch(void* const* d_in, const int* in_sizes, int n_in,
                              void* d_out, int out_size, void* d_ws, size_t ws_size,
                              hipStream_t stream) {
    const float* h       = (const float*)d_in[0];
    const float* emb_rel = (const float*)d_in[1];
    const float* fc1     = (const float*)d_in[2];   // [D, 3D]
    const float* fc2     = (const float*)d_in[3];   // [1, D]
    const float* loopw   = (const float*)d_in[4];   // [D, D]
    const int*   esrc    = (const int*)d_in[5];
    const int*   edst    = (const int*)d_in[6];
    const int*   etyp    = (const int*)d_in[7];
    float* out = (float*)d_out;
    float* ws  = (float*)d_ws;

    float*    w       = ws + OFF_W;
    float*    s1      = ws + OFF_S1;
    float*    s2      = ws + OFF_S2;
    float*    s3      = ws + OFF_S3;
    int*      counts  = (int*)(ws + OFF_COUNTS);
    unsigned* csr     = (unsigned*)(ws + OFF_CSR);
    u16*      hb      = (u16*)(ws + OFF_HB);

    // 1: MFMA self-loop GEMM (writes out) + zero counters + w vector
    k_prep<<<GEMM_BLOCKS + ZERO_BLOCKS + 1, 256, 0, stream>>>(
        fc1, fc2, loopw, h, w, counts, out);

    // 2: fused atomic CSR fill + scores/cast
    k_fused<<<FILL_BLOCKS + SCORE_BLOCKS, 256, 0, stream>>>(
        esrc, edst, etyp, counts, csr, h, emb_rel, w, s1, s2, s3, hb);

    // 3: single-pass softmax gather (RMW out)
    k_gather<<<(N_NODES * 16 + 255) / 256, 256, 0, stream>>>(
        hb, counts, csr, s1, s2, s3, out);
}

// Round 13
// 170.141 us; speedup vs baseline: 1.1972x; 1.0123x over previous
//
#include <hip/hip_runtime.h>

#define N_NODES 50000
#define N_EDGES 600000
#define D 128
#define N_RELS 460
#define CAP_LOG 6            // 64 CSR slots per node (max degree ~35 for Poisson(12))

typedef unsigned short u16;
typedef __attribute__((ext_vector_type(8))) short bf16x8;   // 8 bf16 (4 VGPRs)
typedef __attribute__((ext_vector_type(4))) float f32x4;

// workspace layout (element offsets, 4-byte elements)
enum : int {
    OFF_W      = 0,          //   384 floats  (w = fc1^T @ fc2^T, split w1|w2|w3)
    OFF_S1     = 384,        // 50000 floats
    OFF_S2     = 50384,      // 50000 floats
    OFF_S3     = 100384,     //   460 floats + pad
    OFF_COUNTS = 100864,     // 50000*16 ints (one counter per 64B line)
    OFF_CSR    = 900864,     // 50000*64 uints (padded CSR: src(16b) | typ(16b))
    OFF_HB     = 4100864,    // 6400000 bf16 = 3200000 float slots (h in bf16)
};                           // total ~27.9 MiB

#define NODE_WAVES   12500   // 4 rows per wave
#define REL_WAVES    115     // 460 rels, 4 per wave
#define SCORE_BLOCKS 3154    // ceil((NODE_WAVES+REL_WAVES)/4)
#define GEMM_BLOCKS  782     // ceil(50000/64)
#define ZERO_BLOCKS  196     // 196*256 threads * 4 int4 >= 200000 int4
#define FILL_BLOCKS  293     // ceil(75000/256): 8 edges per thread
#define WT_STRIDE    136     // LDS row stride (bf16 elems): 272B, 16B-aligned b128

__device__ __forceinline__ u16 f2bf(float f) {
    unsigned u = __float_as_uint(f);
    unsigned r = u + 0x7FFFu + ((u >> 16) & 1u);   // RNE
    return (u16)(r >> 16);
}
__device__ __forceinline__ float blo(unsigned u) { return __uint_as_float(u << 16); }
__device__ __forceinline__ float bhi(unsigned u) { return __uint_as_float(u & 0xFFFF0000u); }

// ---------- K0: prep — {MFMA self-loop GEMM + bf16 cast emit} + {zero counters} + {w} ----------
// gemm: out = h @ loop_weight via bf16 MFMA; the bf16 A-fragments are stored to hb
//       (free cast: conversion already needed for MFMA).
//       A-frag: A[m=lane&15][k=quad*8+j]; B-frag: B[k=quad*8+j][n=lane&15];
//       C/D: D[m=quad*4+reg][n=lane&15].
__global__ __launch_bounds__(256) void k_prep(
        const float* __restrict__ fc1, const float* __restrict__ fc2,
        const float* __restrict__ W, const float* __restrict__ h,
        float* __restrict__ w, int* __restrict__ counts,
        u16* __restrict__ hb, float* __restrict__ out) {
    __shared__ u16 Ws[D * WT_STRIDE];                   // 34 KiB
    int t = threadIdx.x;
    if (blockIdx.x < GEMM_BLOCKS) {
        // stage W transposed: Ws[n*136 + k] = bf16(W[k][n])
        for (int i = t; i < (D * D) / 4; i += 256) {    // 4096 float4-units
            float4 v = ((const float4*)W)[i];
            int k  = i >> 5;                            // 32 float4 per row
            int n0 = (i & 31) * 4;
            Ws[(n0 + 0) * WT_STRIDE + k] = f2bf(v.x);
            Ws[(n0 + 1) * WT_STRIDE + k] = f2bf(v.y);
            Ws[(n0 + 2) * WT_STRIDE + k] = f2bf(v.z);
            Ws[(n0 + 3) * WT_STRIDE + k] = f2bf(v.w);
        }
        __syncthreads();

        int wave = t >> 6, lane = t & 63;
        int quad = lane >> 4, m16 = lane & 15;
        int nbase = blockIdx.x * 64 + wave * 16;

        f32x4 acc[8];
        #pragma unroll
        for (int cg = 0; cg < 8; ++cg) acc[cg] = (f32x4){0.f, 0.f, 0.f, 0.f};

        int arow = nbase + m16;
        if (arow >= N_NODES) arow = N_NODES - 1;        // clamp; dup hb writes benign
        const float* aptr = h + (size_t)arow * D + quad * 8;
        u16* hbp = hb + (size_t)arow * D + quad * 8;

        #pragma unroll
        for (int k0 = 0; k0 < D; k0 += 32) {
            float4 a0 = *(const float4*)(aptr + k0);
            float4 a1 = *(const float4*)(aptr + k0 + 4);
            bf16x8 a;
            a[0] = (short)f2bf(a0.x); a[1] = (short)f2bf(a0.y);
            a[2] = (short)f2bf(a0.z); a[3] = (short)f2bf(a0.w);
            a[4] = (short)f2bf(a1.x); a[5] = (short)f2bf(a1.y);
            a[6] = (short)f2bf(a1.z); a[7] = (short)f2bf(a1.w);
            *(bf16x8*)(hbp + k0) = a;                   // free bf16 cast emit (16B)
            #pragma unroll
            for (int cg = 0; cg < 8; ++cg) {
                bf16x8 bb = *(const bf16x8*)(&Ws[(cg * 16 + m16) * WT_STRIDE + k0 + quad * 8]);
                acc[cg] = __builtin_amdgcn_mfma_f32_16x16x32_bf16(a, bb, acc[cg], 0, 0, 0);
            }
        }
        #pragma unroll
        for (int reg = 0; reg < 4; ++reg) {
            int row = nbase + quad * 4 + reg;
            if (row < N_NODES) {
                #pragma unroll
                for (int cg = 0; cg < 8; ++cg)
                    out[(size_t)row * D + cg * 16 + m16] = acc[cg][reg];
            }
        }
    } else if (blockIdx.x < GEMM_BLOCKS + ZERO_BLOCKS) {
        // zero 800000 line-padded counters via 4 int4/thread
        int i4 = (blockIdx.x - GEMM_BLOCKS) * 256 + t;
        #pragma unroll
        for (int rep = 0; rep < 4; ++rep) {
            int idx = i4 * 4 + rep;
            if (idx * 4 < N_NODES * 16)
                ((int4*)counts)[idx] = make_int4(0, 0, 0, 0);
        }
    } else {
        // w[j] = sum_k fc2[k] * fc1[k][j]
        for (int j = t; j < 3 * D; j += 256) {
            float acc = 0.f;
            for (int k = 0; k < D; ++k) acc += fc2[k] * fc1[k * 3 * D + j];
            w[j] = acc;
        }
    }
}

// ---------- K1: fused {atomic CSR fill, 8 edges/thread} + {scores from bf16 hb} ----------
__global__ __launch_bounds__(256) void k_fused(
        const int* __restrict__ src, const int* __restrict__ dst,
        const int* __restrict__ typ, int* __restrict__ counts,
        unsigned* __restrict__ csr,
        const u16* __restrict__ hb, const float* __restrict__ emb_rel,
        const float* __restrict__ w,
        float* __restrict__ s1, float* __restrict__ s2, float* __restrict__ s3) {
    if (blockIdx.x < FILL_BLOCKS) {
        // ---- CSR fill with line-padded atomic rank: 8 independent chains/thread ----
        int i = blockIdx.x * blockDim.x + threadIdx.x;
        if (i >= N_EDGES / 8) return;
        int4 da = ((const int4*)dst)[2 * i],     db = ((const int4*)dst)[2 * i + 1];
        int4 sa = ((const int4*)src)[2 * i],     sb = ((const int4*)src)[2 * i + 1];
        int4 ta = ((const int4*)typ)[2 * i],     tb = ((const int4*)typ)[2 * i + 1];
        int l0 = atomicAdd(&counts[da.x << 4], 1);
        int l1 = atomicAdd(&counts[da.y << 4], 1);
        int l2 = atomicAdd(&counts[da.z << 4], 1);
        int l3 = atomicAdd(&counts[da.w << 4], 1);
        int l4 = atomicAdd(&counts[db.x << 4], 1);
        int l5 = atomicAdd(&counts[db.y << 4], 1);
        int l6 = atomicAdd(&counts[db.z << 4], 1);
        int l7 = atomicAdd(&counts[db.w << 4], 1);
        csr[(da.x << CAP_LOG) + l0] = (unsigned)sa.x | ((unsigned)ta.x << 16);
        csr[(da.y << CAP_LOG) + l1] = (unsigned)sa.y | ((unsigned)ta.y << 16);
        csr[(da.z << CAP_LOG) + l2] = (unsigned)sa.z | ((unsigned)ta.z << 16);
        csr[(da.w << CAP_LOG) + l3] = (unsigned)sa.w | ((unsigned)ta.w << 16);
        csr[(db.x << CAP_LOG) + l4] = (unsigned)sb.x | ((unsigned)tb.x << 16);
        csr[(db.y << CAP_LOG) + l5] = (unsigned)sb.y | ((unsigned)tb.y << 16);
        csr[(db.z << CAP_LOG) + l6] = (unsigned)sb.z | ((unsigned)tb.z << 16);
        csr[(db.w << CAP_LOG) + l7] = (unsigned)sb.w | ((unsigned)tb.w << 16);
    } else {
        // ---- node scores from bf16 hb (4 rows/wave); rel s3 from fp32 emb_rel ----
        int wv = ((blockIdx.x - FILL_BLOCKS) * blockDim.x + threadIdx.x) >> 6;
        int l  = threadIdx.x & 63;
        int sub = l >> 4;                     // which of the wave's 4 rows
        int q   = l & 15;                     // 16 lanes x 8 elems = 128/row
        if (wv < NODE_WAVES) {
            int r = wv * 4 + sub;
            uint4 pk = ((const uint4*)hb)[(size_t)r * 16 + q];   // 8 bf16
            float4 w10 = *(const float4*)(w + q * 8);
            float4 w11 = *(const float4*)(w + q * 8 + 4);
            float4 w20 = *(const float4*)(w + D + q * 8);
            float4 w21 = *(const float4*)(w + D + q * 8 + 4);
            float a1 = blo(pk.x) * w10.x + bhi(pk.x) * w10.y
                     + blo(pk.y) * w10.z + bhi(pk.y) * w10.w
                     + blo(pk.z) * w11.x + bhi(pk.z) * w11.y
                     + blo(pk.w) * w11.z + bhi(pk.w) * w11.w;
            float a2 = blo(pk.x) * w20.x + bhi(pk.x) * w20.y
                     + blo(pk.y) * w20.z + bhi(pk.y) * w20.w
                     + blo(pk.z) * w21.x + bhi(pk.z) * w21.y
                     + blo(pk.w) * w21.z + bhi(pk.w) * w21.w;
            #pragma unroll
            for (int o = 8; o; o >>= 1) { a1 += __shfl_xor(a1, o, 16); a2 += __shfl_xor(a2, o, 16); }
            if (q == 0) { s1[r] = a1; s2[r] = a2; }
        } else if (wv < NODE_WAVES + REL_WAVES) {
            int r = (wv - NODE_WAVES) * 4 + sub;          // 460 = 115*4 exact
            const float* rp = emb_rel + (size_t)r * D + q * 8;
            float4 r0 = *(const float4*)rp;
            float4 r1 = *(const float4*)(rp + 4);
            float4 w30 = *(const float4*)(w + 2 * D + q * 8);
            float4 w31 = *(const float4*)(w + 2 * D + q * 8 + 4);
            float a3 = r0.x * w30.x + r0.y * w30.y + r0.z * w30.z + r0.w * w30.w
                     + r1.x * w31.x + r1.y * w31.y + r1.z * w31.z + r1.w * w31.w;
            #pragma unroll
            for (int o = 8; o; o >>= 1) a3 += __shfl_xor(a3, o, 16);
            if (q == 0) s3[r] = a3;
        }
    }
}

#define ROWACC(uu, cc)                                                         \
    accA.x += (cc) * blo((uu).x);  accA.y += (cc) * bhi((uu).x);               \
    accA.z += (cc) * blo((uu).y);  accA.w += (cc) * bhi((uu).y);               \
    accB.x += (cc) * blo((uu).z);  accB.y += (cc) * bhi((uu).z);               \
    accB.z += (cc) * blo((uu).w);  accB.w += (cc) * bhi((uu).w);

// ---------- K2: single-pass gather — on-the-fly exp, normalize at end ----------
__global__ void k_gather(const u16* __restrict__ hb, const int* __restrict__ counts,
                         const unsigned* __restrict__ csr,
                         const float* __restrict__ s1, const float* __restrict__ s2,
                         const float* __restrict__ s3, float* __restrict__ out) {
    int n  = (blockIdx.x * blockDim.x + threadIdx.x) >> 4;
    int gl = threadIdx.x & 15;
    if (n >= N_NODES) return;
    int deg = counts[n << 4];
    if (deg == 0) return;                                // deg 0: out = h@W only
    int beg = n << CAP_LOG;
    int end = beg + deg;

    float s2n = s2[n];
    float den = 0.f;
    f32x4 accA = {0.f, 0.f, 0.f, 0.f}, accB = {0.f, 0.f, 0.f, 0.f};

    for (int cb = beg; cb < end; cb += 16) {
        int i = cb + gl;
        int msrc = 0; float mex = 0.f;
        if (i < end) {
            unsigned p = csr[i];
            msrc = (int)(p & 0xFFFFu);
            float x = s1[msrc] + s2n + s3[p >> 16];
            float lv = (x > 0.f) ? x : 0.01f * x;
            mex = __expf(lv);                            // |x| small; shift-invariant
        }
        den += mex;                                      // lane-local; reduced at end
        int cnt = min(16, end - cb);
        int j = 0;
        for (; j + 7 < cnt; j += 8) {                    // 8 loads in flight
            int aa[8]; float cc[8]; uint4 uu[8];
            #pragma unroll
            for (int u = 0; u < 8; ++u) {
                aa[u] = __shfl(msrc, j + u, 16);
                cc[u] = __shfl(mex,  j + u, 16);
            }
            #pragma unroll
            for (int u = 0; u < 8; ++u)
                uu[u] = ((const uint4*)(hb + (size_t)aa[u] * D))[gl];
            #pragma unroll
            for (int u = 0; u < 8; ++u) { ROWACC(uu[u], cc[u]); }
        }
        for (; j + 3 < cnt; j += 4) {
            int aa[4]; float cc[4]; uint4 uu[4];
            #pragma unroll
            for (int u = 0; u < 4; ++u) {
                aa[u] = __shfl(msrc, j + u, 16);
                cc[u] = __shfl(mex,  j + u, 16);
            }
            #pragma unroll
            for (int u = 0; u < 4; ++u)
                uu[u] = ((const uint4*)(hb + (size_t)aa[u] * D))[gl];
            #pragma unroll
            for (int u = 0; u < 4; ++u) { ROWACC(uu[u], cc[u]); }
        }
        for (; j < cnt; ++j) {
            int   a0 = __shfl(msrc, j, 16);
            float c0 = __shfl(mex, j, 16);
            uint4 u0 = ((const uint4*)(hb + (size_t)a0 * D))[gl];
            ROWACC(u0, c0);
        }
    }
    #pragma unroll
    for (int o = 8; o; o >>= 1) den += __shfl_xor(den, o, 16);
    float inv = 1.f / den;

    // non-temporal RMW of out (ext_vector f32x4: accepted by the builtin):
    // don't evict hot hb from L2
    f32x4* op = (f32x4*)(out + (size_t)n * D + gl * 8);
    f32x4 o0 = __builtin_nontemporal_load(op);
    f32x4 o1 = __builtin_nontemporal_load(op + 1);
    o0 += accA * inv;
    o1 += accB * inv;
    __builtin_nontemporal_store(o0, op);
    __builtin_nontemporal_store(o1, op + 1);
}

extern "C" void kernel_launch(void* const* d_in, const int* in_sizes, int n_in,
                              void* d_out, int out_size, void* d_ws, size_t ws_size,
                              hipStream_t stream) {
    const float* h       = (const float*)d_in[0];
    const float* emb_rel = (const float*)d_in[1];
    const float* fc1     = (const float*)d_in[2];   // [D, 3D]
    const float* fc2     = (const float*)d_in[3];   // [1, D]
    const float* loopw   = (const float*)d_in[4];   // [D, D]
    const int*   esrc    = (const int*)d_in[5];
    const int*   edst    = (const int*)d_in[6];
    const int*   etyp    = (const int*)d_in[7];
    float* out = (float*)d_out;
    float* ws  = (float*)d_ws;

    float*    w       = ws + OFF_W;
    float*    s1      = ws + OFF_S1;
    float*    s2      = ws + OFF_S2;
    float*    s3      = ws + OFF_S3;
    int*      counts  = (int*)(ws + OFF_COUNTS);
    unsigned* csr     = (unsigned*)(ws + OFF_CSR);
    u16*      hb      = (u16*)(ws + OFF_HB);

    // 1: MFMA self-loop GEMM (writes out + hb) + zero counters + w vector
    k_prep<<<GEMM_BLOCKS + ZERO_BLOCKS + 1, 256, 0, stream>>>(
        fc1, fc2, loopw, h, w, counts, hb, out);

    // 2: fused atomic CSR fill (8 edges/thread) + scores from bf16 hb
    k_fused<<<FILL_BLOCKS + SCORE_BLOCKS, 256, 0, stream>>>(
        esrc, edst, etyp, counts, csr, hb, emb_rel, w, s1, s2, s3);

    // 3: single-pass softmax gather (non-temporal RMW out)
    k_gather<<<(N_NODES * 16 + 255) / 256, 256, 0, stream>>>(
        hb, counts, csr, s1, s2, s3, out);
}